// Round 1
// baseline (567.512 us; speedup 1.0000x reference)
//
#include <hip/hip_runtime.h>
#include <hip/hip_bf16.h>
#include <math.h>
#include <stdint.h>

typedef __hip_bfloat16 bf16;
typedef __attribute__((ext_vector_type(8))) short short8;   // 8 x bf16 (4 VGPRs)
typedef __attribute__((ext_vector_type(4))) float f32x4;

#define NB 16384
#define HID 768
#define EPS_LN 1e-5f
#define LAM_INIT 0.2f       // 0.8 - 0.6*exp(-0.3*0)

__device__ __forceinline__ float bf2f(bf16 x){ return __bfloat162float(x); }
__device__ __forceinline__ bf16  f2bf(float x){ return __float2bfloat16(x); }
__device__ __forceinline__ float bfbits(uint32_t lo16){ return __uint_as_float(lo16 << 16); }
__device__ __forceinline__ uint32_t f2bfbits(float x){
  union { float f; uint32_t u; } v; v.f = x;
  uint32_t u = v.u;
  uint32_t r = (u + 0x7fff + ((u >> 16) & 1)) >> 16;   // RNE
  return r;
}

template<typename T> __device__ __forceinline__ float ldv(const void* p, int i);
template<> __device__ __forceinline__ float ldv<float>(const void* p, int i){ return ((const float*)p)[i]; }
template<> __device__ __forceinline__ float ldv<bf16 >(const void* p, int i){ return bf2f(((const bf16*)p)[i]); }

template<typename T> __device__ __forceinline__ void stv(T* p, float v);
template<> __device__ __forceinline__ void stv<float>(float* p, float v){ *p = v; }
template<> __device__ __forceinline__ void stv<bf16 >(bf16*  p, float v){ *p = f2bf(v); }

__device__ __forceinline__ void async_copy16(void* lds, const void* g){
  __builtin_amdgcn_global_load_lds(
      (const __attribute__((address_space(1))) unsigned int*)g,
      (__attribute__((address_space(3))) unsigned int*)lds, 16, 0, 0);
}

__device__ __forceinline__ float wred64(float v){
  #pragma unroll
  for (int m = 1; m <= 32; m <<= 1) v += __shfl_xor(v, m, 64);
  return v;
}
__device__ __forceinline__ float wred32(float v){   // butterfly within each 32-lane half
  #pragma unroll
  for (int m = 1; m <= 16; m <<= 1) v += __shfl_xor(v, m, 64);
  return v;
}

// -------- prep (1 wave): dtype detect + lambda + pair-indexed RoPE tables ----
// prep floats: [0]=flag(int), [1]=lam, [16+s*32+p]=cos_p, [128+s*32+p]=sin_p (p<24)
__global__ void prep_kernel(const void* etab, const void* lq1, const void* lk1,
                            const void* lq2, const void* lk2, float* prep){
  const int lane = threadIdx.x;
  const uint32_t* p = (const uint32_t*)((const char*)etab + 512);
  int v = (lane < 16) ? (int)p[lane] : 0;
  #pragma unroll
  for (int m = 1; m <= 32; m <<= 1) v |= __shfl_xor(v, m, 64);
  const int isbf = (v == 0) ? 1 : 0;
  if (lane == 0) ((int*)prep)[0] = isbf;

  float p1 = 0.f, p2 = 0.f;
  if (lane < 48){
    if (isbf){ p1 = ldv<bf16>(lq1,lane)*ldv<bf16>(lk1,lane); p2 = ldv<bf16>(lq2,lane)*ldv<bf16>(lk2,lane); }
    else     { p1 = ldv<float>(lq1,lane)*ldv<float>(lk1,lane); p2 = ldv<float>(lq2,lane)*ldv<float>(lk2,lane); }
  }
  p1 = wred64(p1); p2 = wred64(p2);
  if (lane == 0) prep[1] = expf(p1) - expf(p2) + LAM_INIT;

  if (lane < 24){
    float invf = powf(10000.f, -(float)(2*lane)/48.f);
    #pragma unroll
    for (int s=0;s<3;++s){
      float ang = (float)s*invf;
      prep[16  + s*32 + lane] = cosf(ang);
      prep[128 + s*32 + lane] = sinf(ang);
    }
  }
}

// ---------------- weight transpose: (K,N) row-major -> bf16 (N,K) row-major --
template<typename T>
__device__ __forceinline__ void transpose_body(bf16 (*tile)[33], const void* src, bf16* dst){
  const int n0 = blockIdx.x*32, k0 = blockIdx.y*32;
  const int tx = threadIdx.x, ty = threadIdx.y;
  #pragma unroll
  for (int r=0;r<4;++r)
    tile[ty + 8*r][tx] = f2bf(ldv<T>(src, (k0 + ty + 8*r)*HID + n0 + tx));
  __syncthreads();
  #pragma unroll
  for (int r=0;r<4;++r)
    dst[(size_t)(n0 + ty + 8*r)*HID + k0 + tx] = tile[tx][ty + 8*r];
}

__global__ __launch_bounds__(256) void transpose_weights(
    const void* Wq, const void* Wk, const void* Wv, const void* Wo,
    bf16* __restrict__ WqkvT, bf16* __restrict__ WoT, const float* prep)
{
  __shared__ bf16 tile[32][33];
  const int z = blockIdx.z;
  const void* src = (z==0)? Wq : (z==1)? Wk : (z==2)? Wv : Wo;
  bf16* dst = (z<3)? (WqkvT + (size_t)z*HID*HID) : WoT;
  if (((const int*)prep)[0]) transpose_body<bf16 >(tile, src, dst);
  else                       transpose_body<float>(tile, src, dst);
}

// ---------------- fused embed -> FC1 -> LayerNorm -> exact GELU --------------
template<typename T>
__device__ __forceinline__ void embed_body(
    float (*s_emb)[32], float (*s_h)[HID],
    const int* eidx, const void* conf, const void* etab, const void* W1,
    const void* b1, const void* lng, const void* lnb, bf16* hout, int tok0)
{
  const int tid = threadIdx.x;
  const int tl0 = blockIdx.x * 16;     // chunk-local token base

  for (int i = tid; i < 16*32; i += 256) {
    int t = i >> 5, e = i & 31;
    int tt = tok0 + tl0 + t;           // global token
    int id = eidx[tt]; if (id < 0) id = 8;
    float cf = ldv<T>(conf, tt);
    s_emb[t][e] = ldv<T>(etab, id*32 + e) * cf;
  }
  __syncthreads();

  float acc0[16], acc1[16], acc2[16];
  #pragma unroll
  for (int t=0;t<16;++t){ acc0[t]=0.f; acc1[t]=0.f; acc2[t]=0.f; }
  const int c0 = tid, c1 = tid+256, c2 = tid+512;
  #pragma unroll 4
  for (int e=0;e<32;++e){
    float w0 = ldv<T>(W1, e*HID+c0), w1 = ldv<T>(W1, e*HID+c1), w2 = ldv<T>(W1, e*HID+c2);
    #pragma unroll
    for (int t=0;t<16;++t){
      float em = s_emb[t][e];
      acc0[t] += em*w0; acc1[t] += em*w1; acc2[t] += em*w2;
    }
  }
  float bb0 = ldv<T>(b1,c0), bb1 = ldv<T>(b1,c1), bb2 = ldv<T>(b1,c2);
  #pragma unroll
  for (int t=0;t<16;++t){
    s_h[t][c0] = acc0[t]+bb0; s_h[t][c1] = acc1[t]+bb1; s_h[t][c2] = acc2[t]+bb2;
  }
  __syncthreads();

  const int wv = tid>>6, lane = tid&63;
  for (int t = wv; t < 16; t += 4) {
    float x[12]; float sm = 0.f, sq = 0.f;
    #pragma unroll
    for (int j=0;j<12;++j){ float xv = s_h[t][lane + 64*j]; x[j]=xv; sm += xv; sq += xv*xv; }
    sm = wred64(sm); sq = wred64(sq);
    float mu  = sm * (1.f/768.f);
    float var = sq * (1.f/768.f) - mu*mu;
    float rs  = rsqrtf(fmaxf(var, 0.f) + EPS_LN);
    #pragma unroll
    for (int j=0;j<12;++j){
      int col = lane + 64*j;
      float y  = (x[j]-mu)*rs*ldv<T>(lng,col) + ldv<T>(lnb,col);
      float ge = 0.5f*y*(1.f + erff(y*0.70710678118f));
      hout[(size_t)(tl0+t)*HID + col] = f2bf(ge);
    }
  }
}

__global__ __launch_bounds__(256) void embed_fc1_ln_gelu(
    const int* __restrict__ eidx, const void* conf, const void* etab,
    const void* W1, const void* b1, const void* lng, const void* lnb,
    bf16* __restrict__ hout, int tok0, const float* prep)
{
  __shared__ float s_emb[16][32];
  __shared__ float s_h[16][HID];       // 48 KB
  if (((const int*)prep)[0]) embed_body<bf16 >(s_emb, s_h, eidx, conf, etab, W1, b1, lng, lnb, hout, tok0);
  else                       embed_body<float>(s_emb, s_h, eidx, conf, etab, W1, b1, lng, lnb, hout, tok0);
}

// ------- 256x256 8-phase MFMA GEMM (m201-style T2+T3+T4+T5) ------------------
// 512 threads = 8 waves (2Mx4N), BK=64, 128 KB LDS (2 dbuf x (A 32K + B 32K)).
// Per iteration: tiles a=2it (buf0, phases p1-p4) and b=2it+1 (buf1, p5-p8).
// Phase = {12 ds_read_b128 quadrant frags; stage ONE half-tile (2 x
// global_load_lds dwordx4); s_barrier; lgkmcnt(0); setprio(1) 16 MFMA
// setprio(0); [vmcnt(4) at p4/p8]; s_barrier}.  Stage slots:
//   p1: A1@b  ->buf1   p2: B1@b  ->buf1   p3: A0@a+2->buf0   p4: B0@a+2->buf0
//   p5: A1@a+2->buf0   p6: B1@a+2->buf0   p7: A0@b+2->buf1   p8: B0@b+2->buf1
// Race audit: each stage is issued strictly after the barrier retiring the
// last ds_reads of its destination half; vmcnt(4) at p4 proves tile b landed
// (leaves p3,p4 in flight), at p8 proves tile a+2 landed (leaves p7,p8).
// vmcnt never drains to 0 mid-loop (T4).  Barriers are asm-volatile with
// "memory" clobber so LDS loads / global_load_lds cannot be moved across.
// Bank-conflict-free LDS (measured 0): chunk c of row r stored at phys chunk
// c^(r&7); staging keeps linear LDS dest and permutes the GLOBAL source chunk
// (same 128B segment -> still coalesced); readers XOR k-offset with (row&7)*8.
#define EBAR()  asm volatile("s_barrier" ::: "memory")
#define WVMC(N) asm volatile("s_waitcnt vmcnt(" #N ")" ::: "memory")

template<int MH, int NH, int BUFI>
__device__ __forceinline__ void phase_mm(const char* lbase, f32x4 (&acc)[2][2][4][2],
                                         int wqm, int wqn, int l15, int k0, int k1)
{
  const bf16* pA = (const bf16*)(lbase + BUFI*65536);
  const bf16* pB = (const bf16*)(lbase + BUFI*65536 + 32768);
  const int rb = MH*128 + wqm*64 + l15;
  const int cb = NH*128 + wqn*32 + l15;
  short8 a0[4], a1[4], b0v[2], b1v[2];
  #pragma unroll
  for (int i=0;i<4;++i){
    a0[i] = *(const short8*)&pA[(rb + i*16)*64 + k0];
    a1[i] = *(const short8*)&pA[(rb + i*16)*64 + k1];
  }
  #pragma unroll
  for (int j=0;j<2;++j){
    b0v[j] = *(const short8*)&pB[(cb + j*16)*64 + k0];
    b1v[j] = *(const short8*)&pB[(cb + j*16)*64 + k1];
  }
  EBAR();                                            // BAR1 (align MFMA clusters)
  asm volatile("s_waitcnt lgkmcnt(0)" ::: "memory");
  __builtin_amdgcn_sched_barrier(0);
  __builtin_amdgcn_s_setprio(1);
  #pragma unroll
  for (int i=0;i<4;++i)
    #pragma unroll
    for (int j=0;j<2;++j){
      acc[MH][NH][i][j] = __builtin_amdgcn_mfma_f32_16x16x32_bf16(a0[i], b0v[j], acc[MH][NH][i][j], 0,0,0);
      acc[MH][NH][i][j] = __builtin_amdgcn_mfma_f32_16x16x32_bf16(a1[i], b1v[j], acc[MH][NH][i][j], 0,0,0);
    }
  __builtin_amdgcn_s_setprio(0);
  __builtin_amdgcn_sched_barrier(0);
}

template<typename OutT>
__device__ __forceinline__ void gemm_body(char* lbase,
    const bf16* __restrict__ A, const bf16* __restrict__ Bt, OutT* __restrict__ C,
    int K, int lda, int ldb, int ldc, int MT, int NT)
{
  int bid = blockIdx.x;
  int mt, nt;
  if ((MT & 7) == 0) {
    int x = bid & 7, j = bid >> 3;
    nt = j % NT;
    mt = x * (MT >> 3) + j / NT;
  } else { nt = bid % NT; mt = bid / NT; }

  const int tid  = threadIdx.x;
  const int wave = tid >> 6, lane = tid & 63;
  const int wqm = wave >> 2, wqn = wave & 3;          // 2 x 4 wave grid
  const int l15 = lane & 15;
  const int r8  = lane >> 3;
  const int csw = ((lane & 7) ^ r8) * 16;             // pre-swizzled global chunk
  const int m0 = mt*256, n0 = nt*256;
  const int k0 = ((lane >> 4)*8) ^ ((lane & 7) << 3); // reader phys-k, ks=0
  const int k1 = k0 ^ 32;                             // ks=32

  const char* Ag = (const char*)(A + (size_t)m0 * lda);
  const char* Bg = (const char*)(Bt + (size_t)n0 * ldb);

  // per-thread staging offsets: t = h*2+ii, rowgroup rg = h*16 + wave*2 + ii
  size_t offA[4], offB[4];
  int dstoff[4];
  #pragma unroll
  for (int t=0;t<4;++t){
    const int rg = (t>>1)*16 + wave*2 + (t&1);
    offA[t]  = (size_t)(rg*8 + r8) * lda * 2 + csw;
    offB[t]  = (size_t)(rg*8 + r8) * ldb * 2 + csw;
    dstoff[t] = rg*1024 + lane*16;                    // linear wave dest
  }

  #define SH(BUFI_, AB_, H_, KT_) do {                                          \
    _Pragma("unroll")                                                           \
    for (int ii=0; ii<2; ++ii){                                                 \
      const int t_ = (H_)*2 + ii;                                               \
      async_copy16(lbase + (BUFI_)*65536 + (AB_)*32768 + dstoff[t_],            \
                   ((AB_) ? (Bg + offB[t_]) : (Ag + offA[t_])) + (size_t)(KT_)*2); \
    } } while(0)

  f32x4 acc[2][2][4][2];
  #pragma unroll
  for (int a_=0;a_<2;++a_)
    #pragma unroll
    for (int b_=0;b_<2;++b_)
      #pragma unroll
      for (int i=0;i<4;++i)
        #pragma unroll
        for (int j=0;j<2;++j) acc[a_][b_][i][j] = (f32x4){0.f,0.f,0.f,0.f};

  // prologue: tile0 complete + tile1 A0,B0 (12 loads/thread)
  SH(0,0,0, 0); SH(0,1,0, 0); SH(0,0,1, 0); SH(0,1,1, 0);
  SH(1,0,0, 64); SH(1,1,0, 64);
  WVMC(4);                                            // tile0 landed
  EBAR();

  const int NIT = K >> 7;                             // K must be multiple of 128
  for (int it = 0; it < NIT; ++it){
    const bool more = (it+1 < NIT);
    const int kb  = (2*it+1) << 6;
    const int ka2 = (2*it+2) << 6;
    const int kb2 = (2*it+3) << 6;

    SH(1,0,1, kb);                                    // p1: A1@b -> buf1
    phase_mm<0,0,0>(lbase, acc, wqm, wqn, l15, k0, k1);
    EBAR();

    SH(1,1,1, kb);                                    // p2: B1@b -> buf1
    phase_mm<0,1,0>(lbase, acc, wqm, wqn, l15, k0, k1);
    EBAR();

    if (more) SH(0,0,0, ka2);                         // p3: A0@a+2 -> buf0
    phase_mm<1,0,0>(lbase, acc, wqm, wqn, l15, k0, k1);
    EBAR();

    if (more) SH(0,1,0, ka2);                         // p4: B0@a+2 -> buf0
    phase_mm<1,1,0>(lbase, acc, wqm, wqn, l15, k0, k1);
    if (more) { WVMC(4); } else { WVMC(0); }          // tile b landed
    EBAR();

    if (more) SH(0,0,1, ka2);                         // p5: A1@a+2 -> buf0
    phase_mm<0,0,1>(lbase, acc, wqm, wqn, l15, k0, k1);
    EBAR();

    if (more) SH(0,1,1, ka2);                         // p6: B1@a+2 -> buf0
    phase_mm<0,1,1>(lbase, acc, wqm, wqn, l15, k0, k1);
    EBAR();

    if (more) SH(1,0,0, kb2);                         // p7: A0@b+2 -> buf1
    phase_mm<1,0,1>(lbase, acc, wqm, wqn, l15, k0, k1);
    EBAR();

    if (more) SH(1,1,0, kb2);                         // p8: B0@b+2 -> buf1
    phase_mm<1,1,1>(lbase, acc, wqm, wqn, l15, k0, k1);
    if (more) { WVMC(4); }                            // tile a+2 landed
    EBAR();
  }
  #undef SH

  // epilogue: C/D layout col=lane&15, row=(lane>>4)*4+reg
  const int rb4 = (lane >> 4)*4, cl = lane & 15;
  #pragma unroll
  for (int MH=0; MH<2; ++MH)
    #pragma unroll
    for (int i=0;i<4;++i)
      #pragma unroll
      for (int r=0;r<4;++r){
        const int grow = m0 + MH*128 + wqm*64 + i*16 + rb4 + r;
        OutT* Cp = C + (size_t)grow*ldc + n0 + wqn*32 + cl;
        #pragma unroll
        for (int NH=0; NH<2; ++NH)
          #pragma unroll
          for (int j=0;j<2;++j)
            stv<OutT>(Cp + NH*128 + j*16, acc[MH][NH][i][j][r]);
      }
}

__global__ __launch_bounds__(512, 2) void gemm_int(
    const bf16* __restrict__ A, const bf16* __restrict__ Bt, bf16* __restrict__ C,
    int K, int lda, int ldb, int ldc, int MT, int NT)
{
  __shared__ __align__(16) char lds[131072];   // 128 KB: 2 dbuf x (A 32K + B 32K)
  gemm_body<bf16>(lds, A, Bt, C, K, lda, ldb, ldc, MT, NT);
}

__global__ __launch_bounds__(512, 2) void gemm_final(
    const bf16* __restrict__ A, const bf16* __restrict__ Bt, void* C,
    int K, int lda, int ldb, int ldc, int MT, int NT, const float* prep)
{
  __shared__ __align__(16) char lds[131072];
  if (((const int*)prep)[0]) gemm_body<bf16 >(lds, A, Bt, (bf16*)C,  K, lda, ldb, ldc, MT, NT);
  else                       gemm_body<float>(lds, A, Bt, (float*)C, K, lda, ldb, ldc, MT, NT);
}

// ---------------- attention, pair-per-lane layout ----------------------------
template<typename T>
__device__ __forceinline__ void attn_body(
    const bf16* __restrict__ qkv, const int* __restrict__ eidx,
    const void* subw, bf16* __restrict__ obar, int b0, const float* prep)
{
  const int gw = blockIdx.x*4 + (threadIdx.x>>6);
  const int bl = gw >> 3, h = gw & 7;      // chunk-local batch row, head
  const int bg = b0 + bl;                  // global batch row
  const int lane = threadIdx.x & 63;
  const int g = lane >> 5;                 // q/k half (0/1)
  const int p = lane & 31;                 // pair index within half
  const bool pa = (p < 24);

  float npad[3];
  #pragma unroll
  for (int s=0;s<3;++s){ int id = eidx[bg*3+s]; npad[s] = (id < 0 || id == 8) ? 0.f : 1.f; }
  float denom = npad[0]+npad[1]+npad[2]; if (denom < 1.f) denom = 1.f;
  const float lam = prep[1];

  float cs[3], sn[3];
  #pragma unroll
  for (int s=0;s<3;++s){
    cs[s] = pa ? prep[16  + s*32 + p] : 0.f;
    sn[s] = pa ? prep[128 + s*32 + p] : 0.f;
  }

  const char* base = (const char*)(qkv + (size_t)bl*3*2304);
  float qr1[3], qr2[3], kr1[3], kr2[3];
  const int qoff = (2*h+g)*48 + 2*p;       // element offset within token row
  #pragma unroll
  for (int s=0;s<3;++s){
    uint32_t qu = pa ? *(const uint32_t*)(base + (s*2304 + qoff)*2) : 0u;
    uint32_t ku = pa ? *(const uint32_t*)(base + (s*2304 + 768 + qoff)*2) : 0u;
    float q1 = bfbits(qu & 0xffff), q2 = bfbits(qu >> 16);
    float k1 = bfbits(ku & 0xffff), k2 = bfbits(ku >> 16);
    qr1[s] = q1*cs[s] - q2*sn[s];  qr2[s] = q1*sn[s] + q2*cs[s];
    kr1[s] = k1*cs[s] - k2*sn[s];  kr2[s] = k1*sn[s] + k2*cs[s];
  }

  const float scale = 0.14433756729740643f;  // 48^-0.5
  float att[3][3];
  #pragma unroll
  for (int sq=0; sq<3; ++sq){
    float sc[3];
    #pragma unroll
    for (int sk=0; sk<3; ++sk){
      float pr = wred32(qr1[sq]*kr1[sk] + qr2[sq]*kr2[sk]);
      sc[sk] = pr*scale + (npad[sk] > 0.f ? 0.f : -1e30f);
    }
    float mx = fmaxf(sc[0], fmaxf(sc[1], sc[2]));
    float e0 = expf(sc[0]-mx), e1 = expf(sc[1]-mx), e2 = expf(sc[2]-mx);
    float inv = 1.f/(e0+e1+e2);
    att[sq][0]=e0*inv; att[sq][1]=e1*inv; att[sq][2]=e2*inv;
  }
  float diff[3][3];
  #pragma unroll
  for (int sq=0; sq<3; ++sq)
    #pragma unroll
    for (int sk=0; sk<3; ++sk){
      float other = __shfl_xor(att[sq][sk], 32, 64);
      diff[sq][sk] = (g==0) ? (att[sq][sk] - lam*other) : (other - lam*att[sq][sk]);
    }

  const bool va = (lane < 48);
  float v1[3], v2[3];
  #pragma unroll
  for (int s=0;s<3;++s){
    uint32_t vu = va ? *(const uint32_t*)(base + (s*2304 + 1536 + h*96 + 2*lane)*2) : 0u;
    v1[s] = bfbits(vu & 0xffff); v2[s] = bfbits(vu >> 16);
  }
  float sw1 = va ? ldv<T>(subw, 2*lane)   : 0.f;
  float sw2 = va ? ldv<T>(subw, 2*lane+1) : 0.f;

  float a1 = 0.f, a2 = 0.f;
  #pragma unroll
  for (int sq=0; sq<3; ++sq){
    float o1 = diff[sq][0]*v1[0] + diff[sq][1]*v1[1] + diff[sq][2]*v1[2];
    float o2 = diff[sq][0]*v2[0] + diff[sq][1]*v2[1] + diff[sq][2]*v2[2];
    float ss = wred64(o1*o1 + o2*o2);             // sum over 96 dims
    float rms = sqrtf(ss*(1.f/96.f) + 1e-5f);
    float kk = 0.8f / rms;                        // includes *(1-LAMBDA_INIT)
    a1 += npad[sq]*o1*kk*sw1;
    a2 += npad[sq]*o2*kk*sw2;
  }
  const float idn = 1.f/denom;
  if (va){
    uint32_t w = f2bfbits(a1*idn) | (f2bfbits(a2*idn) << 16);
    *(uint32_t*)((char*)obar + ((size_t)bg*HID + h*96 + 2*lane)*2) = w;
  }
}

__global__ __launch_bounds__(256) void attn_kernel(
    const bf16* __restrict__ qkv, const int* __restrict__ eidx,
    const void* subw, bf16* __restrict__ obar, int b0, const float* prep)
{
  if (((const int*)prep)[0]) attn_body<bf16 >(qkv, eidx, subw, obar, b0, prep);
  else                       attn_body<float>(qkv, eidx, subw, obar, b0, prep);
}

// ---------------- launch ----------------------------------------------------
extern "C" void kernel_launch(void* const* d_in, const int* in_sizes, int n_in,
                              void* d_out, int out_size, void* d_ws, size_t ws_size,
                              hipStream_t stream)
{
  const int*  eidx = (const int*) d_in[0];
  const void* conf = d_in[1];
  const void* etab = d_in[2];
  const void* W1   = d_in[3];
  const void* b1   = d_in[4];
  const void* lng  = d_in[5];
  const void* lnb  = d_in[6];
  const void* Wq   = d_in[7];
  const void* Wk   = d_in[8];
  const void* Wv   = d_in[9];
  const void* Wo   = d_in[10];
  const void* lq1  = d_in[11];
  const void* lk1  = d_in[12];
  const void* lq2  = d_in[13];
  const void* lk2  = d_in[14];
  const void* subw = d_in[15];

  // ws layout: [prep 4KB][obar][WqkvT][WoT][hbuf][qkv]
  const size_t PREP_B = 4096ull;
  const size_t OBAR_B = 25165824ull, WQKVT_B = 3538944ull, WOT_B = 1179648ull;
  const size_t FIXED  = PREP_B + OBAR_B + WQKVT_B + WOT_B;

  char*  ws   = (char*)d_ws;
  float* prep = (float*)ws;
  bf16*  obar = (bf16*)(ws + PREP_B);
  bf16* WqkvT = (bf16*)(ws + PREP_B + OBAR_B);
  bf16* WoT   = (bf16*)(ws + PREP_B + OBAR_B + WQKVT_B);

  // largest power-of-two chunk of batch rows that fits (min 256: ctok % 256)
  int CB = NB;
  while (CB > 256 && FIXED + (size_t)CB*18432ull > ws_size) CB >>= 1;

  bf16* hbuf = (bf16*)(ws + FIXED);
  bf16* qkv  = (bf16*)(ws + FIXED + (size_t)CB*4608ull);

  prep_kernel<<<1, 64, 0, stream>>>(etab, lq1, lk1, lq2, lk2, prep);
  transpose_weights<<<dim3(24,24,4), dim3(32,8), 0, stream>>>(Wq, Wk, Wv, Wo, WqkvT, WoT, prep);

  const int nchunks = NB / CB;
  const int ctok = 3*CB;                      // tokens per chunk (mult of 768)
  for (int c = 0; c < nchunks; ++c) {
    const int b0 = c*CB, tok0 = b0*3;
    const int MT = ctok/256, NT = 9;          // 256x256 tiles, N = 2304
    embed_fc1_ln_gelu<<<ctok/16, 256, 0, stream>>>(eidx, conf, etab, W1, b1, lng, lnb, hbuf, tok0, prep);
    gemm_int<<<MT*NT, 512, 0, stream>>>(hbuf, WqkvT, qkv, HID, HID, HID, 2304, MT, NT);
    attn_kernel<<<CB*2, 256, 0, stream>>>(qkv, eidx, subw, obar, b0, prep);
  }

  gemm_final<<<64*3, 512, 0, stream>>>(obar, WoT, (void*)d_out, HID, HID, HID, HID, 64, 3, prep);
}

// Round 2
// 495.979 us; speedup vs baseline: 1.1442x; 1.1442x over previous
//
#include <hip/hip_runtime.h>
#include <hip/hip_bf16.h>
#include <math.h>
#include <stdint.h>

typedef __hip_bfloat16 bf16;
typedef __attribute__((ext_vector_type(8))) short short8;   // 8 x bf16 (4 VGPRs)
typedef __attribute__((ext_vector_type(4))) float f32x4;
typedef __attribute__((ext_vector_type(2))) unsigned int u32x2;

#define NB 16384
#define HID 768
#define EPS_LN 1e-5f
#define LAM_INIT 0.2f       // 0.8 - 0.6*exp(-0.3*0)

__device__ __forceinline__ float bf2f(bf16 x){ return __bfloat162float(x); }
__device__ __forceinline__ bf16  f2bf(float x){ return __float2bfloat16(x); }
__device__ __forceinline__ float bfbits(uint32_t lo16){ return __uint_as_float(lo16 << 16); }
__device__ __forceinline__ uint32_t f2bfbits(float x){
  union { float f; uint32_t u; } v; v.f = x;
  uint32_t u = v.u;
  uint32_t r = (u + 0x7fff + ((u >> 16) & 1)) >> 16;   // RNE
  return r;
}

template<typename T> __device__ __forceinline__ float ldv(const void* p, int i);
template<> __device__ __forceinline__ float ldv<float>(const void* p, int i){ return ((const float*)p)[i]; }
template<> __device__ __forceinline__ float ldv<bf16 >(const void* p, int i){ return bf2f(((const bf16*)p)[i]); }

template<typename T> __device__ __forceinline__ void stv(T* p, float v);
template<> __device__ __forceinline__ void stv<float>(float* p, float v){ *p = v; }
template<> __device__ __forceinline__ void stv<bf16 >(bf16*  p, float v){ *p = f2bf(v); }

__device__ __forceinline__ void async_copy16(void* lds, const void* g){
  __builtin_amdgcn_global_load_lds(
      (const __attribute__((address_space(1))) unsigned int*)g,
      (__attribute__((address_space(3))) unsigned int*)lds, 16, 0, 0);
}

__device__ __forceinline__ float wred64(float v){
  #pragma unroll
  for (int m = 1; m <= 32; m <<= 1) v += __shfl_xor(v, m, 64);
  return v;
}

// -------- prep (1 wave): dtype detect + lambda + pair-indexed RoPE tables ----
// prep floats: [0]=flag(int), [1]=lam, [16+s*32+p]=cos_p, [128+s*32+p]=sin_p,
//              [256 + (s*24+p)*2 .. +1] = packed {cos,sin} per pair (p<24)
__global__ void prep_kernel(const void* etab, const void* lq1, const void* lk1,
                            const void* lq2, const void* lk2, float* prep){
  const int lane = threadIdx.x;
  const uint32_t* p = (const uint32_t*)((const char*)etab + 512);
  int v = (lane < 16) ? (int)p[lane] : 0;
  #pragma unroll
  for (int m = 1; m <= 32; m <<= 1) v |= __shfl_xor(v, m, 64);
  const int isbf = (v == 0) ? 1 : 0;
  if (lane == 0) ((int*)prep)[0] = isbf;

  float p1 = 0.f, p2 = 0.f;
  if (lane < 48){
    if (isbf){ p1 = ldv<bf16>(lq1,lane)*ldv<bf16>(lk1,lane); p2 = ldv<bf16>(lq2,lane)*ldv<bf16>(lk2,lane); }
    else     { p1 = ldv<float>(lq1,lane)*ldv<float>(lk1,lane); p2 = ldv<float>(lq2,lane)*ldv<float>(lk2,lane); }
  }
  p1 = wred64(p1); p2 = wred64(p2);
  if (lane == 0) prep[1] = expf(p1) - expf(p2) + LAM_INIT;

  if (lane < 24){
    float invf = powf(10000.f, -(float)(2*lane)/48.f);
    #pragma unroll
    for (int s=0;s<3;++s){
      float ang = (float)s*invf;
      float c = cosf(ang), sv = sinf(ang);
      prep[16  + s*32 + lane] = c;
      prep[128 + s*32 + lane] = sv;
      prep[256 + (s*24 + lane)*2    ] = c;
      prep[256 + (s*24 + lane)*2 + 1] = sv;
    }
  }
}

// ---------------- weight transpose: (K,N) row-major -> bf16 (N,K) row-major --
template<typename T>
__device__ __forceinline__ void transpose_body(bf16 (*tile)[33], const void* src, bf16* dst){
  const int n0 = blockIdx.x*32, k0 = blockIdx.y*32;
  const int tx = threadIdx.x, ty = threadIdx.y;
  #pragma unroll
  for (int r=0;r<4;++r)
    tile[ty + 8*r][tx] = f2bf(ldv<T>(src, (k0 + ty + 8*r)*HID + n0 + tx));
  __syncthreads();
  #pragma unroll
  for (int r=0;r<4;++r)
    dst[(size_t)(n0 + ty + 8*r)*HID + k0 + tx] = tile[tx][ty + 8*r];
}

__global__ __launch_bounds__(256) void transpose_weights(
    const void* Wq, const void* Wk, const void* Wv, const void* Wo,
    bf16* __restrict__ WqkvT, bf16* __restrict__ WoT, const float* prep)
{
  __shared__ bf16 tile[32][33];
  const int z = blockIdx.z;
  const void* src = (z==0)? Wq : (z==1)? Wk : (z==2)? Wv : Wo;
  bf16* dst = (z<3)? (WqkvT + (size_t)z*HID*HID) : WoT;
  if (((const int*)prep)[0]) transpose_body<bf16 >(tile, src, dst);
  else                       transpose_body<float>(tile, src, dst);
}

// ---------------- fused embed -> FC1 -> LayerNorm -> exact GELU --------------
template<typename T>
__device__ __forceinline__ void embed_body(
    float (*s_emb)[32], float (*s_h)[HID],
    const int* eidx, const void* conf, const void* etab, const void* W1,
    const void* b1, const void* lng, const void* lnb, bf16* hout, int tok0)
{
  const int tid = threadIdx.x;
  const int tl0 = blockIdx.x * 16;     // chunk-local token base

  for (int i = tid; i < 16*32; i += 256) {
    int t = i >> 5, e = i & 31;
    int tt = tok0 + tl0 + t;           // global token
    int id = eidx[tt]; if (id < 0) id = 8;
    float cf = ldv<T>(conf, tt);
    s_emb[t][e] = ldv<T>(etab, id*32 + e) * cf;
  }
  __syncthreads();

  float acc0[16], acc1[16], acc2[16];
  #pragma unroll
  for (int t=0;t<16;++t){ acc0[t]=0.f; acc1[t]=0.f; acc2[t]=0.f; }
  const int c0 = tid, c1 = tid+256, c2 = tid+512;
  #pragma unroll 4
  for (int e=0;e<32;++e){
    float w0 = ldv<T>(W1, e*HID+c0), w1 = ldv<T>(W1, e*HID+c1), w2 = ldv<T>(W1, e*HID+c2);
    #pragma unroll
    for (int t=0;t<16;++t){
      float em = s_emb[t][e];
      acc0[t] += em*w0; acc1[t] += em*w1; acc2[t] += em*w2;
    }
  }
  float bb0 = ldv<T>(b1,c0), bb1 = ldv<T>(b1,c1), bb2 = ldv<T>(b1,c2);
  #pragma unroll
  for (int t=0;t<16;++t){
    s_h[t][c0] = acc0[t]+bb0; s_h[t][c1] = acc1[t]+bb1; s_h[t][c2] = acc2[t]+bb2;
  }
  __syncthreads();

  const int wv = tid>>6, lane = tid&63;
  for (int t = wv; t < 16; t += 4) {
    float x[12]; float sm = 0.f, sq = 0.f;
    #pragma unroll
    for (int j=0;j<12;++j){ float xv = s_h[t][lane + 64*j]; x[j]=xv; sm += xv; sq += xv*xv; }
    sm = wred64(sm); sq = wred64(sq);
    float mu  = sm * (1.f/768.f);
    float var = sq * (1.f/768.f) - mu*mu;
    float rs  = rsqrtf(fmaxf(var, 0.f) + EPS_LN);
    #pragma unroll
    for (int j=0;j<12;++j){
      int col = lane + 64*j;
      float y  = (x[j]-mu)*rs*ldv<T>(lng,col) + ldv<T>(lnb,col);
      float ge = 0.5f*y*(1.f + erff(y*0.70710678118f));
      hout[(size_t)(tl0+t)*HID + col] = f2bf(ge);
    }
  }
}

__global__ __launch_bounds__(256) void embed_fc1_ln_gelu(
    const int* __restrict__ eidx, const void* conf, const void* etab,
    const void* W1, const void* b1, const void* lng, const void* lnb,
    bf16* __restrict__ hout, int tok0, const float* prep)
{
  __shared__ float s_emb[16][32];
  __shared__ float s_h[16][HID];       // 48 KB
  if (((const int*)prep)[0]) embed_body<bf16 >(s_emb, s_h, eidx, conf, etab, W1, b1, lng, lnb, hout, tok0);
  else                       embed_body<float>(s_emb, s_h, eidx, conf, etab, W1, b1, lng, lnb, hout, tok0);
}

// ------- 128x128 MFMA GEMM: dbuf pipeline + XCD swizzle + LDS XOR swizzle ----
// (round-0 proven version: 2 blocks/CU, ~743 TF at this shape)
template<typename OutT>
__device__ __forceinline__ void gemm_body(
    bf16* sA, bf16* sB,     // each 2*128*64 elements (two buffers)
    const bf16* __restrict__ A, const bf16* __restrict__ Bt, OutT* __restrict__ C,
    int K, int lda, int ldb, int ldc, int MT, int NT)
{
  int bid = blockIdx.x;
  int mt, nt;
  if ((MT & 7) == 0) {
    int x = bid & 7, j = bid >> 3;
    nt = j % NT;
    mt = x * (MT >> 3) + j / NT;
  } else { nt = bid % NT; mt = bid / NT; }

  const int tid = threadIdx.x;
  const int wave = tid >> 6, lane = tid & 63;
  const int m0 = mt * 128, n0 = nt * 128;
  const int wm = wave >> 1, wn = wave & 1;

  f32x4 acc[4][4];
  #pragma unroll
  for (int i=0;i<4;++i)
    #pragma unroll
    for (int j=0;j<4;++j) acc[i][j] = (f32x4){0.f,0.f,0.f,0.f};

  const char* Ag = (const char*)(A  + (size_t)m0 * lda);
  const char* Bg = (const char*)(Bt + (size_t)n0 * ldb);
  const int r8  = lane >> 3;                       // row within 8-row group (0..7)
  const int cBx = ((lane & 7) ^ r8) * 16;          // XOR-permuted k-group source

  #define STAGE(buf, kt) do {                                                   \
    _Pragma("unroll")                                                           \
    for (int ii = 0; ii < 4; ++ii) {                                            \
      const int i_ = wave*4 + ii;                                               \
      const int row_ = i_*8 + r8;                                               \
      async_copy16((char*)sA + (buf)*16384 + i_*1024 + lane*16,                 \
                   Ag + ((size_t)row_*lda + (kt))*2 + cBx);                     \
      async_copy16((char*)sB + (buf)*16384 + i_*1024 + lane*16,                 \
                   Bg + ((size_t)row_*ldb + (kt))*2 + cBx);                     \
    }                                                                           \
  } while(0)

  STAGE(0, 0);
  int cur = 0;
  const int rxor = (lane & 7) << 3;                // reader phys-k XOR (row&7)*8
  for (int kt = 0; kt < K; kt += 64) {
    __syncthreads();
    if (kt + 64 < K) STAGE(cur^1, kt + 64);   // prefetch overlaps compute below
    const bf16* pA = sA + cur*8192;
    const bf16* pB = sB + cur*8192;
    #pragma unroll
    for (int ks = 0; ks < 64; ks += 32) {
      const int kq = (ks + (lane >> 4)*8) ^ rxor;
      short8 af[4], bfv[4];
      #pragma unroll
      for (int i=0;i<4;++i)
        af[i]  = *(const short8*)&pA[(wm*64 + i*16 + (lane&15))*64 + kq];
      #pragma unroll
      for (int j=0;j<4;++j)
        bfv[j] = *(const short8*)&pB[(wn*64 + j*16 + (lane&15))*64 + kq];
      #pragma unroll
      for (int i=0;i<4;++i)
        #pragma unroll
        for (int j=0;j<4;++j)
          acc[i][j] = __builtin_amdgcn_mfma_f32_16x16x32_bf16(af[i], bfv[j], acc[i][j], 0,0,0);
    }
    cur ^= 1;
  }
  #undef STAGE

  const int rb = (lane>>4)*4, cb = lane & 15;   // C/D: col=lane&15, row=quad*4+reg
  #pragma unroll
  for (int i=0;i<4;++i)
    #pragma unroll
    for (int r=0;r<4;++r) {
      const int grow = m0 + wm*64 + i*16 + rb + r;
      OutT* Cp = C + (size_t)grow*ldc + n0 + wn*64 + cb;
      #pragma unroll
      for (int j=0;j<4;++j) stv<OutT>(Cp + j*16, acc[i][j][r]);
    }
}

__global__ __launch_bounds__(256) void gemm_int(
    const bf16* __restrict__ A, const bf16* __restrict__ Bt, bf16* __restrict__ C,
    int K, int lda, int ldb, int ldc, int MT, int NT)
{
  __shared__ __align__(16) bf16 sA[2*128*64];   // 32 KB
  __shared__ __align__(16) bf16 sB[2*128*64];   // 32 KB
  gemm_body<bf16>(sA, sB, A, Bt, C, K, lda, ldb, ldc, MT, NT);
}

__global__ __launch_bounds__(256) void gemm_final(
    const bf16* __restrict__ A, const bf16* __restrict__ Bt, void* C,
    int K, int lda, int ldb, int ldc, int MT, int NT, const float* prep)
{
  __shared__ __align__(16) bf16 sA[2*128*64];
  __shared__ __align__(16) bf16 sB[2*128*64];
  if (((const int*)prep)[0]) gemm_body<bf16 >(sA, sB, A, Bt, (bf16*)C,  K, lda, ldb, ldc, MT, NT);
  else                       gemm_body<float>(sA, sB, A, Bt, (float*)C, K, lda, ldb, ldc, MT, NT);
}

// ---------------- attention: one wave per batch row (all 8 heads) ------------
// lane = h*8 + u, u = g*4 + qd.  Each lane owns a 12-dim slice:
//   QK phase: (h,g) half's dims [qd*12, qd*12+12) = pairs [qd*6, qd*6+6)
//   PV phase: head h's output dims [u*12, u*12+12)
// Scores: in-lane 6-pair partials -> 2-shfl quad reduce (x9).  g-swap: xor4.
// rms: 3-shfl reduce over the 8 lanes of h.  36 shfl/wave for 8 heads
// (vs 72/head-wave before); every qkv byte read exactly once, 8B loads.
template<typename T>
__device__ __forceinline__ void attn_body(
    const bf16* __restrict__ qkv, const int* __restrict__ eidx,
    const void* subw, bf16* __restrict__ obar, int b0, const float* prep)
{
  const int bl = blockIdx.x*4 + (threadIdx.x>>6);   // chunk-local batch row
  const int bg = b0 + bl;                           // global batch row
  const int lane = threadIdx.x & 63;
  const int h  = lane >> 3;
  const int u  = lane & 7;
  const int g  = u >> 2;
  const int qd = u & 3;

  float npad[3];
  #pragma unroll
  for (int s=0;s<3;++s){ int id = eidx[bg*3+s]; npad[s] = (id < 0 || id == 8) ? 0.f : 1.f; }
  float denom = npad[0]+npad[1]+npad[2]; if (denom < 1.f) denom = 1.f;
  const float lam = prep[1];
  const float2* pk = (const float2*)(prep + 256);

  const char* base = (const char*)(qkv + (size_t)bl*3*2304);
  const int qoff = (2*h+g)*48 + qd*12;              // element offset in token row

  // ---- load q,k slices: 3 tokens x 24B each ----
  u32x2 qw[3][3], kw[3][3];
  #pragma unroll
  for (int s=0;s<3;++s){
    const char* qp = base + (size_t)(s*2304 + qoff)*2;
    const char* kp = qp + 768*2;
    #pragma unroll
    for (int t=0;t<3;++t){
      qw[s][t] = *(const u32x2*)(qp + t*8);
      kw[s][t] = *(const u32x2*)(kp + t*8);
    }
  }

  // ---- RoPE + score partials (6 pairs in-lane) ----
  float sc[3][3];
  #pragma unroll
  for (int a=0;a<3;++a){ sc[a][0]=0.f; sc[a][1]=0.f; sc[a][2]=0.f; }
  #pragma unroll
  for (int j=0;j<6;++j){
    float qr1[3], qr2[3], kr1[3], kr2[3];
    #pragma unroll
    for (int s=0;s<3;++s){
      float2 cs = pk[s*24 + qd*6 + j];
      uint32_t qu = qw[s][j>>1][j&1], ku = kw[s][j>>1][j&1];
      float q1 = bfbits(qu & 0xffffu), q2 = bfbits(qu >> 16);
      float k1 = bfbits(ku & 0xffffu), k2 = bfbits(ku >> 16);
      qr1[s] = q1*cs.x - q2*cs.y;  qr2[s] = q1*cs.y + q2*cs.x;
      kr1[s] = k1*cs.x - k2*cs.y;  kr2[s] = k1*cs.y + k2*cs.x;
    }
    #pragma unroll
    for (int a=0;a<3;++a)
      #pragma unroll
      for (int b=0;b<3;++b) sc[a][b] += qr1[a]*kr1[b] + qr2[a]*kr2[b];
  }
  // quad reduce: lanes {qd=0..3} of each (h,g)
  #pragma unroll
  for (int a=0;a<3;++a)
    #pragma unroll
    for (int b=0;b<3;++b){
      float v = sc[a][b];
      v += __shfl_xor(v, 1, 64);
      v += __shfl_xor(v, 2, 64);
      sc[a][b] = v;
    }

  // ---- softmax (per lane, per (h,g)) ----
  const float scale = 0.14433756729740643f;  // 48^-0.5
  float att[3][3];
  #pragma unroll
  for (int a=0;a<3;++a){
    float s0 = sc[a][0]*scale + (npad[0] > 0.f ? 0.f : -1e30f);
    float s1 = sc[a][1]*scale + (npad[1] > 0.f ? 0.f : -1e30f);
    float s2 = sc[a][2]*scale + (npad[2] > 0.f ? 0.f : -1e30f);
    float mx = fmaxf(s0, fmaxf(s1, s2));
    float e0 = expf(s0-mx), e1 = expf(s1-mx), e2 = expf(s2-mx);
    float inv = 1.f/(e0+e1+e2);
    att[a][0]=e0*inv; att[a][1]=e1*inv; att[a][2]=e2*inv;
  }
  // ---- differential: exchange with other half (lane^4) ----
  float diff[3][3];
  #pragma unroll
  for (int a=0;a<3;++a)
    #pragma unroll
    for (int b=0;b<3;++b){
      float other = __shfl_xor(att[a][b], 4, 64);
      diff[a][b] = (g==0) ? (att[a][b] - lam*other) : (other - lam*att[a][b]);
    }

  // ---- PV: lane owns output dims [u*12, u*12+12) of head h ----
  const int vd = u*12;
  float vv[3][12];
  #pragma unroll
  for (int s=0;s<3;++s){
    const char* vp = base + (size_t)(s*2304 + 1536 + h*96 + vd)*2;
    #pragma unroll
    for (int t=0;t<3;++t){
      u32x2 w = *(const u32x2*)(vp + t*8);
      vv[s][t*4+0] = bfbits(w[0] & 0xffffu);
      vv[s][t*4+1] = bfbits(w[0] >> 16);
      vv[s][t*4+2] = bfbits(w[1] & 0xffffu);
      vv[s][t*4+3] = bfbits(w[1] >> 16);
    }
  }
  float sw[12];
  #pragma unroll
  for (int d=0;d<12;++d) sw[d] = ldv<T>(subw, vd + d);

  float acc[12];
  #pragma unroll
  for (int d=0;d<12;++d) acc[d] = 0.f;
  #pragma unroll
  for (int a=0;a<3;++a){
    float o[12]; float ss = 0.f;
    #pragma unroll
    for (int d=0;d<12;++d){
      o[d] = diff[a][0]*vv[0][d] + diff[a][1]*vv[1][d] + diff[a][2]*vv[2][d];
      ss += o[d]*o[d];
    }
    ss += __shfl_xor(ss, 1, 64);
    ss += __shfl_xor(ss, 2, 64);
    ss += __shfl_xor(ss, 4, 64);                  // sum over 96 dims of head h
    float rms = sqrtf(ss*(1.f/96.f) + 1e-5f);
    float kk  = npad[a]*0.8f/rms;                 // includes *(1-LAMBDA_INIT)
    #pragma unroll
    for (int d=0;d<12;++d) acc[d] += o[d]*kk*sw[d];
  }
  const float idn = 1.f/denom;
  char* op = (char*)obar + (size_t)(bg*HID + h*96 + vd)*2;
  #pragma unroll
  for (int t=0;t<3;++t){
    u32x2 w;
    w[0] = f2bfbits(acc[t*4+0]*idn) | (f2bfbits(acc[t*4+1]*idn) << 16);
    w[1] = f2bfbits(acc[t*4+2]*idn) | (f2bfbits(acc[t*4+3]*idn) << 16);
    *(u32x2*)(op + t*8) = w;
  }
}

__global__ __launch_bounds__(256) void attn_kernel(
    const bf16* __restrict__ qkv, const int* __restrict__ eidx,
    const void* subw, bf16* __restrict__ obar, int b0, const float* prep)
{
  if (((const int*)prep)[0]) attn_body<bf16 >(qkv, eidx, subw, obar, b0, prep);
  else                       attn_body<float>(qkv, eidx, subw, obar, b0, prep);
}

// ---------------- launch ----------------------------------------------------
extern "C" void kernel_launch(void* const* d_in, const int* in_sizes, int n_in,
                              void* d_out, int out_size, void* d_ws, size_t ws_size,
                              hipStream_t stream)
{
  const int*  eidx = (const int*) d_in[0];
  const void* conf = d_in[1];
  const void* etab = d_in[2];
  const void* W1   = d_in[3];
  const void* b1   = d_in[4];
  const void* lng  = d_in[5];
  const void* lnb  = d_in[6];
  const void* Wq   = d_in[7];
  const void* Wk   = d_in[8];
  const void* Wv   = d_in[9];
  const void* Wo   = d_in[10];
  const void* lq1  = d_in[11];
  const void* lk1  = d_in[12];
  const void* lq2  = d_in[13];
  const void* lk2  = d_in[14];
  const void* subw = d_in[15];

  // ws layout: [prep 4KB][obar][WqkvT][WoT][hbuf][qkv]
  const size_t PREP_B = 4096ull;
  const size_t OBAR_B = 25165824ull, WQKVT_B = 3538944ull, WOT_B = 1179648ull;
  const size_t FIXED  = PREP_B + OBAR_B + WQKVT_B + WOT_B;

  char*  ws   = (char*)d_ws;
  float* prep = (float*)ws;
  bf16*  obar = (bf16*)(ws + PREP_B);
  bf16* WqkvT = (bf16*)(ws + PREP_B + OBAR_B);
  bf16* WoT   = (bf16*)(ws + PREP_B + OBAR_B + WQKVT_B);

  // largest power-of-two chunk of batch rows that fits (min 128)
  int CB = NB;
  while (CB > 128 && FIXED + (size_t)CB*18432ull > ws_size) CB >>= 1;

  bf16* hbuf = (bf16*)(ws + FIXED);
  bf16* qkv  = (bf16*)(ws + FIXED + (size_t)CB*4608ull);

  prep_kernel<<<1, 64, 0, stream>>>(etab, lq1, lk1, lq2, lk2, prep);
  transpose_weights<<<dim3(24,24,4), dim3(32,8), 0, stream>>>(Wq, Wk, Wv, Wo, WqkvT, WoT, prep);

  const int nchunks = NB / CB;
  const int ctok = 3*CB;                      // tokens per chunk (mult of 384)
  for (int c = 0; c < nchunks; ++c) {
    const int b0 = c*CB, tok0 = b0*3;
    const int MT = ctok/128, NT = 18;
    embed_fc1_ln_gelu<<<ctok/16, 256, 0, stream>>>(eidx, conf, etab, W1, b1, lng, lnb, hbuf, tok0, prep);
    gemm_int<<<MT*NT, 256, 0, stream>>>(hbuf, WqkvT, qkv, HID, HID, HID, 2304, MT, NT);
    attn_kernel<<<CB/4, 256, 0, stream>>>(qkv, eidx, subw, obar, b0, prep);
  }

  gemm_final<<<128*6, 256, 0, stream>>>(obar, WoT, (void*)d_out, HID, HID, HID, HID, 128, 6, prep);
}

// Round 3
// 484.385 us; speedup vs baseline: 1.1716x; 1.0239x over previous
//
#include <hip/hip_runtime.h>
#include <hip/hip_bf16.h>
#include <math.h>
#include <stdint.h>

typedef __hip_bfloat16 bf16;
typedef __attribute__((ext_vector_type(8))) short short8;   // 8 x bf16 (4 VGPRs)
typedef __attribute__((ext_vector_type(4))) float f32x4;
typedef __attribute__((ext_vector_type(2))) unsigned int u32x2;

#define NB 16384
#define HID 768
#define EPS_LN 1e-5f
#define LAM_INIT 0.2f       // 0.8 - 0.6*exp(-0.3*0)

__device__ __forceinline__ float bf2f(bf16 x){ return __bfloat162float(x); }
__device__ __forceinline__ bf16  f2bf(float x){ return __float2bfloat16(x); }
__device__ __forceinline__ float bfbits(uint32_t lo16){ return __uint_as_float(lo16 << 16); }
__device__ __forceinline__ uint32_t f2bfbits(float x){
  union { float f; uint32_t u; } v; v.f = x;
  uint32_t u = v.u;
  uint32_t r = (u + 0x7fff + ((u >> 16) & 1)) >> 16;   // RNE
  return r;
}

template<typename T> __device__ __forceinline__ float ldv(const void* p, int i);
template<> __device__ __forceinline__ float ldv<float>(const void* p, int i){ return ((const float*)p)[i]; }
template<> __device__ __forceinline__ float ldv<bf16 >(const void* p, int i){ return bf2f(((const bf16*)p)[i]); }

template<typename T> __device__ __forceinline__ void stv(T* p, float v);
template<> __device__ __forceinline__ void stv<float>(float* p, float v){ *p = v; }
template<> __device__ __forceinline__ void stv<bf16 >(bf16*  p, float v){ *p = f2bf(v); }

__device__ __forceinline__ void async_copy16(void* lds, const void* g){
  __builtin_amdgcn_global_load_lds(
      (const __attribute__((address_space(1))) unsigned int*)g,
      (__attribute__((address_space(3))) unsigned int*)lds, 16, 0, 0);
}

__device__ __forceinline__ float wred64(float v){
  #pragma unroll
  for (int m = 1; m <= 32; m <<= 1) v += __shfl_xor(v, m, 64);
  return v;
}

// -------- prep (1 block): dtype detect + lambda + RoPE tables + E1 table -----
// prep floats:
//   [0]=flag(int), [1]=lam
//   [16+s*32+p]=cos, [128+s*32+p]=sin            (legacy layout, p<24)
//   [256 + (s*24+p)*2 .. +1] = packed {cos,sin}  (p<24)
//   [512+id]=mean(E1[id]), [528+id]=E[E1[id]^2], [544+id]=E[E1[id]*b1]
//   [560]=mean(b1), [561]=E[b1^2]
//   [1024 .. 1024+9*768) = E1 = etab @ W1  (9 x 768, f32)
// Key identity: emb@W1 = conf * (etab[id]@W1), so FC1 collapses to a 9x768
// table lookup and the LN stats are closed-form in conf.
template<typename T>
__device__ __forceinline__ void prep_body(float* sE1, const void* etab, const void* W1,
                                          const void* b1, float* prep){
  const int tid = threadIdx.x;
  for (int id = 0; id < 9; ++id){
    #pragma unroll
    for (int q = 0; q < 3; ++q){
      const int cc = tid + q*256;
      float s = 0.f;
      #pragma unroll
      for (int e = 0; e < 32; ++e) s += ldv<T>(etab, id*32+e) * ldv<T>(W1, e*HID+cc);
      sE1[id*HID + cc] = s;
      prep[1024 + id*HID + cc] = s;
    }
  }
  __syncthreads();
  const int wave = tid >> 6, lane = tid & 63;
  float bv[12];
  #pragma unroll
  for (int j = 0; j < 12; ++j) bv[j] = ldv<T>(b1, lane + 64*j);
  for (int id = wave; id < 9; id += 4){
    float su = 0.f, suu = 0.f, sub = 0.f;
    #pragma unroll
    for (int j = 0; j < 12; ++j){
      float v = sE1[id*HID + lane + 64*j];
      su += v; suu += v*v; sub += v*bv[j];
    }
    su = wred64(su); suu = wred64(suu); sub = wred64(sub);
    if (lane == 0){
      prep[512+id] = su  * (1.f/768.f);
      prep[528+id] = suu * (1.f/768.f);
      prep[544+id] = sub * (1.f/768.f);
    }
  }
  if (wave == 0){
    float sb = 0.f, sbb = 0.f;
    #pragma unroll
    for (int j = 0; j < 12; ++j){ sb += bv[j]; sbb += bv[j]*bv[j]; }
    sb = wred64(sb); sbb = wred64(sbb);
    if (lane == 0){ prep[560] = sb*(1.f/768.f); prep[561] = sbb*(1.f/768.f); }
  }
}

__global__ __launch_bounds__(256) void prep_kernel(
    const void* etab, const void* W1, const void* b1,
    const void* lq1, const void* lk1, const void* lq2, const void* lk2, float* prep){
  __shared__ float sE1[9*HID];     // 27.6 KB
  __shared__ int s_isbf;
  const int tid = threadIdx.x;
  if (tid < 64){
    const int lane = tid;
    const uint32_t* p = (const uint32_t*)((const char*)etab + 512);
    int v = (lane < 16) ? (int)p[lane] : 0;
    #pragma unroll
    for (int m = 1; m <= 32; m <<= 1) v |= __shfl_xor(v, m, 64);
    const int isbf = (v == 0) ? 1 : 0;
    if (lane == 0){ ((int*)prep)[0] = isbf; s_isbf = isbf; }

    float p1 = 0.f, p2 = 0.f;
    if (lane < 48){
      if (isbf){ p1 = ldv<bf16>(lq1,lane)*ldv<bf16>(lk1,lane); p2 = ldv<bf16>(lq2,lane)*ldv<bf16>(lk2,lane); }
      else     { p1 = ldv<float>(lq1,lane)*ldv<float>(lk1,lane); p2 = ldv<float>(lq2,lane)*ldv<float>(lk2,lane); }
    }
    p1 = wred64(p1); p2 = wred64(p2);
    if (lane == 0) prep[1] = expf(p1) - expf(p2) + LAM_INIT;

    if (lane < 24){
      float invf = powf(10000.f, -(float)(2*lane)/48.f);
      #pragma unroll
      for (int s=0;s<3;++s){
        float ang = (float)s*invf;
        float c = cosf(ang), sv = sinf(ang);
        prep[16  + s*32 + lane] = c;
        prep[128 + s*32 + lane] = sv;
        prep[256 + (s*24 + lane)*2    ] = c;
        prep[256 + (s*24 + lane)*2 + 1] = sv;
      }
    }
  }
  __syncthreads();
  if (s_isbf) prep_body<bf16 >(sE1, etab, W1, b1, prep);
  else        prep_body<float>(sE1, etab, W1, b1, prep);
}

// ---------------- weight transpose: (K,N) row-major -> bf16 (N,K) row-major --
template<typename T>
__device__ __forceinline__ void transpose_body(bf16 (*tile)[33], const void* src, bf16* dst){
  const int n0 = blockIdx.x*32, k0 = blockIdx.y*32;
  const int tx = threadIdx.x, ty = threadIdx.y;
  #pragma unroll
  for (int r=0;r<4;++r)
    tile[ty + 8*r][tx] = f2bf(ldv<T>(src, (k0 + ty + 8*r)*HID + n0 + tx));
  __syncthreads();
  #pragma unroll
  for (int r=0;r<4;++r)
    dst[(size_t)(n0 + ty + 8*r)*HID + k0 + tx] = tile[tx][ty + 8*r];
}

__global__ __launch_bounds__(256) void transpose_weights(
    const void* Wq, const void* Wk, const void* Wv, const void* Wo,
    bf16* __restrict__ WqkvT, bf16* __restrict__ WoT, const float* prep)
{
  __shared__ bf16 tile[32][33];
  const int z = blockIdx.z;
  const void* src = (z==0)? Wq : (z==1)? Wk : (z==2)? Wv : Wo;
  bf16* dst = (z<3)? (WqkvT + (size_t)z*HID*HID) : WoT;
  if (((const int*)prep)[0]) transpose_body<bf16 >(tile, src, dst);
  else                       transpose_body<float>(tile, src, dst);
}

// -------- embed via E1 table: h = gelu(LN(conf*E1[id] + b1)) -----------------
// Closed-form LN stats (no reductions): mu = conf*m_u[id] + m_b,
// E[h^2] = conf^2*s_uu[id] + 2conf*s_ub[id] + s_bb.  Per token per lane:
// 3 float4 loads from the L1-resident 27KB E1 table + 12 fused LN+GELU lanes.
template<typename T>
__device__ __forceinline__ void embed_body(
    const int* eidx, const void* conf, const void* b1, const void* lng,
    const void* lnb, const float* prep, bf16* hout, int tok0)
{
  const int wave = threadIdx.x >> 6, lane = threadIdx.x & 63;
  const int t0 = blockIdx.x*64 + wave*16;
  const int c  = lane*12;
  float bb[12], gg[12], be[12];
  #pragma unroll
  for (int d=0;d<12;++d){ bb[d]=ldv<T>(b1,c+d); gg[d]=ldv<T>(lng,c+d); be[d]=ldv<T>(lnb,c+d); }
  const float m_b = prep[560], s_bb = prep[561];
  const float* E1 = prep + 1024;

  for (int tt = 0; tt < 16; ++tt){
    const int tl = t0 + tt, tg = tok0 + tl;
    int id = eidx[tg]; if (id < 0) id = 8;
    const float cf = ldv<T>(conf, tg);
    const float4* ep = (const float4*)(E1 + id*HID + c);
    float4 u0 = ep[0], u1 = ep[1], u2 = ep[2];
    float u[12] = {u0.x,u0.y,u0.z,u0.w, u1.x,u1.y,u1.z,u1.w, u2.x,u2.y,u2.z,u2.w};
    const float mu  = cf*prep[512+id] + m_b;
    const float ex2 = cf*cf*prep[528+id] + 2.f*cf*prep[544+id] + s_bb;
    const float var = ex2 - mu*mu;
    const float rs  = rsqrtf(fmaxf(var, 0.f) + EPS_LN);
    uint32_t w[6];
    #pragma unroll
    for (int d=0;d<6;++d){
      float x0 = cf*u[2*d]   + bb[2*d];
      float x1 = cf*u[2*d+1] + bb[2*d+1];
      float y0 = (x0-mu)*rs*gg[2*d]   + be[2*d];
      float y1 = (x1-mu)*rs*gg[2*d+1] + be[2*d+1];
      float g0 = 0.5f*y0*(1.f + erff(y0*0.70710678118f));
      float g1 = 0.5f*y1*(1.f + erff(y1*0.70710678118f));
      w[d] = f2bfbits(g0) | (f2bfbits(g1) << 16);
    }
    char* op = (char*)hout + (size_t)(tl*HID + c)*2;
    ((u32x2*)op)[0] = (u32x2){w[0],w[1]};
    ((u32x2*)op)[1] = (u32x2){w[2],w[3]};
    ((u32x2*)op)[2] = (u32x2){w[4],w[5]};
  }
}

__global__ __launch_bounds__(256) void embed_ln_gelu(
    const int* __restrict__ eidx, const void* conf, const void* b1,
    const void* lng, const void* lnb, const float* prep,
    bf16* __restrict__ hout, int tok0)
{
  if (((const int*)prep)[0]) embed_body<bf16 >(eidx, conf, b1, lng, lnb, prep, hout, tok0);
  else                       embed_body<float>(eidx, conf, b1, lng, lnb, prep, hout, tok0);
}

// ------- 128x128 MFMA GEMM: dbuf pipeline + XCD swizzle + LDS XOR swizzle ----
template<typename OutT>
__device__ __forceinline__ void gemm_body(
    bf16* sA, bf16* sB,     // each 2*128*64 elements (two buffers)
    const bf16* __restrict__ A, const bf16* __restrict__ Bt, OutT* __restrict__ C,
    int K, int lda, int ldb, int ldc, int MT, int NT)
{
  int bid = blockIdx.x;
  int mt, nt;
  if ((MT & 7) == 0) {
    int x = bid & 7, j = bid >> 3;
    nt = j % NT;
    mt = x * (MT >> 3) + j / NT;
  } else { nt = bid % NT; mt = bid / NT; }

  const int tid = threadIdx.x;
  const int wave = tid >> 6, lane = tid & 63;
  const int m0 = mt * 128, n0 = nt * 128;
  const int wm = wave >> 1, wn = wave & 1;

  f32x4 acc[4][4];
  #pragma unroll
  for (int i=0;i<4;++i)
    #pragma unroll
    for (int j=0;j<4;++j) acc[i][j] = (f32x4){0.f,0.f,0.f,0.f};

  const char* Ag = (const char*)(A  + (size_t)m0 * lda);
  const char* Bg = (const char*)(Bt + (size_t)n0 * ldb);
  const int r8  = lane >> 3;                       // row within 8-row group (0..7)
  const int cBx = ((lane & 7) ^ r8) * 16;          // XOR-permuted k-group source

  #define STAGE(buf, kt) do {                                                   \
    _Pragma("unroll")                                                           \
    for (int ii = 0; ii < 4; ++ii) {                                            \
      const int i_ = wave*4 + ii;                                               \
      const int row_ = i_*8 + r8;                                               \
      async_copy16((char*)sA + (buf)*16384 + i_*1024 + lane*16,                 \
                   Ag + ((size_t)row_*lda + (kt))*2 + cBx);                     \
      async_copy16((char*)sB + (buf)*16384 + i_*1024 + lane*16,                 \
                   Bg + ((size_t)row_*ldb + (kt))*2 + cBx);                     \
    }                                                                           \
  } while(0)

  STAGE(0, 0);
  int cur = 0;
  const int rxor = (lane & 7) << 3;                // reader phys-k XOR (row&7)*8
  for (int kt = 0; kt < K; kt += 64) {
    __syncthreads();
    if (kt + 64 < K) STAGE(cur^1, kt + 64);   // prefetch overlaps compute below
    const bf16* pA = sA + cur*8192;
    const bf16* pB = sB + cur*8192;
    #pragma unroll
    for (int ks = 0; ks < 64; ks += 32) {
      const int kq = (ks + (lane >> 4)*8) ^ rxor;
      short8 af[4], bfv[4];
      #pragma unroll
      for (int i=0;i<4;++i)
        af[i]  = *(const short8*)&pA[(wm*64 + i*16 + (lane&15))*64 + kq];
      #pragma unroll
      for (int j=0;j<4;++j)
        bfv[j] = *(const short8*)&pB[(wn*64 + j*16 + (lane&15))*64 + kq];
      #pragma unroll
      for (int i=0;i<4;++i)
        #pragma unroll
        for (int j=0;j<4;++j)
          acc[i][j] = __builtin_amdgcn_mfma_f32_16x16x32_bf16(af[i], bfv[j], acc[i][j], 0,0,0);
    }
    cur ^= 1;
  }
  #undef STAGE

  const int rb = (lane>>4)*4, cb = lane & 15;   // C/D: col=lane&15, row=quad*4+reg
  #pragma unroll
  for (int i=0;i<4;++i)
    #pragma unroll
    for (int r=0;r<4;++r) {
      const int grow = m0 + wm*64 + i*16 + rb + r;
      OutT* Cp = C + (size_t)grow*ldc + n0 + wn*64 + cb;
      #pragma unroll
      for (int j=0;j<4;++j) stv<OutT>(Cp + j*16, acc[i][j][r]);
    }
}

__global__ __launch_bounds__(256) void gemm_int(
    const bf16* __restrict__ A, const bf16* __restrict__ Bt, bf16* __restrict__ C,
    int K, int lda, int ldb, int ldc, int MT, int NT)
{
  __shared__ __align__(16) bf16 sA[2*128*64];   // 32 KB
  __shared__ __align__(16) bf16 sB[2*128*64];   // 32 KB
  gemm_body<bf16>(sA, sB, A, Bt, C, K, lda, ldb, ldc, MT, NT);
}

__global__ __launch_bounds__(256) void gemm_final(
    const bf16* __restrict__ A, const bf16* __restrict__ Bt, void* C,
    int K, int lda, int ldb, int ldc, int MT, int NT, const float* prep)
{
  __shared__ __align__(16) bf16 sA[2*128*64];
  __shared__ __align__(16) bf16 sB[2*128*64];
  if (((const int*)prep)[0]) gemm_body<bf16 >(sA, sB, A, Bt, (bf16*)C,  K, lda, ldb, ldc, MT, NT);
  else                       gemm_body<float>(sA, sB, A, Bt, (float*)C, K, lda, ldb, ldc, MT, NT);
}

// ---------------- attention: one wave per batch row (all 8 heads) ------------
// lane = h*8 + u, u = g*4 + qd.  36 shfl/wave for 8 heads; every qkv byte read
// exactly once, 8B loads.
template<typename T>
__device__ __forceinline__ void attn_body(
    const bf16* __restrict__ qkv, const int* __restrict__ eidx,
    const void* subw, bf16* __restrict__ obar, int b0, const float* prep)
{
  const int bl = blockIdx.x*4 + (threadIdx.x>>6);   // chunk-local batch row
  const int bg = b0 + bl;                           // global batch row
  const int lane = threadIdx.x & 63;
  const int h  = lane >> 3;
  const int u  = lane & 7;
  const int g  = u >> 2;
  const int qd = u & 3;

  float npad[3];
  #pragma unroll
  for (int s=0;s<3;++s){ int id = eidx[bg*3+s]; npad[s] = (id < 0 || id == 8) ? 0.f : 1.f; }
  float denom = npad[0]+npad[1]+npad[2]; if (denom < 1.f) denom = 1.f;
  const float lam = prep[1];
  const float2* pk = (const float2*)(prep + 256);

  const char* base = (const char*)(qkv + (size_t)bl*3*2304);
  const int qoff = (2*h+g)*48 + qd*12;              // element offset in token row

  u32x2 qw[3][3], kw[3][3];
  #pragma unroll
  for (int s=0;s<3;++s){
    const char* qp = base + (size_t)(s*2304 + qoff)*2;
    const char* kp = qp + 768*2;
    #pragma unroll
    for (int t=0;t<3;++t){
      qw[s][t] = *(const u32x2*)(qp + t*8);
      kw[s][t] = *(const u32x2*)(kp + t*8);
    }
  }

  float sc[3][3];
  #pragma unroll
  for (int a=0;a<3;++a){ sc[a][0]=0.f; sc[a][1]=0.f; sc[a][2]=0.f; }
  #pragma unroll
  for (int j=0;j<6;++j){
    float qr1[3], qr2[3], kr1[3], kr2[3];
    #pragma unroll
    for (int s=0;s<3;++s){
      float2 cs = pk[s*24 + qd*6 + j];
      uint32_t qu = qw[s][j>>1][j&1], ku = kw[s][j>>1][j&1];
      float q1 = bfbits(qu & 0xffffu), q2 = bfbits(qu >> 16);
      float k1 = bfbits(ku & 0xffffu), k2 = bfbits(ku >> 16);
      qr1[s] = q1*cs.x - q2*cs.y;  qr2[s] = q1*cs.y + q2*cs.x;
      kr1[s] = k1*cs.x - k2*cs.y;  kr2[s] = k1*cs.y + k2*cs.x;
    }
    #pragma unroll
    for (int a=0;a<3;++a)
      #pragma unroll
      for (int b=0;b<3;++b) sc[a][b] += qr1[a]*kr1[b] + qr2[a]*kr2[b];
  }
  #pragma unroll
  for (int a=0;a<3;++a)
    #pragma unroll
    for (int b=0;b<3;++b){
      float v = sc[a][b];
      v += __shfl_xor(v, 1, 64);
      v += __shfl_xor(v, 2, 64);
      sc[a][b] = v;
    }

  const float scale = 0.14433756729740643f;  // 48^-0.5
  float att[3][3];
  #pragma unroll
  for (int a=0;a<3;++a){
    float s0 = sc[a][0]*scale + (npad[0] > 0.f ? 0.f : -1e30f);
    float s1 = sc[a][1]*scale + (npad[1] > 0.f ? 0.f : -1e30f);
    float s2 = sc[a][2]*scale + (npad[2] > 0.f ? 0.f : -1e30f);
    float mx = fmaxf(s0, fmaxf(s1, s2));
    float e0 = expf(s0-mx), e1 = expf(s1-mx), e2 = expf(s2-mx);
    float inv = 1.f/(e0+e1+e2);
    att[a][0]=e0*inv; att[a][1]=e1*inv; att[a][2]=e2*inv;
  }
  float diff[3][3];
  #pragma unroll
  for (int a=0;a<3;++a)
    #pragma unroll
    for (int b=0;b<3;++b){
      float other = __shfl_xor(att[a][b], 4, 64);
      diff[a][b] = (g==0) ? (att[a][b] - lam*other) : (other - lam*att[a][b]);
    }

  const int vd = u*12;
  float vv[3][12];
  #pragma unroll
  for (int s=0;s<3;++s){
    const char* vp = base + (size_t)(s*2304 + 1536 + h*96 + vd)*2;
    #pragma unroll
    for (int t=0;t<3;++t){
      u32x2 w = *(const u32x2*)(vp + t*8);
      vv[s][t*4+0] = bfbits(w[0] & 0xffffu);
      vv[s][t*4+1] = bfbits(w[0] >> 16);
      vv[s][t*4+2] = bfbits(w[1] & 0xffffu);
      vv[s][t*4+3] = bfbits(w[1] >> 16);
    }
  }
  float sw[12];
  #pragma unroll
  for (int d=0;d<12;++d) sw[d] = ldv<T>(subw, vd + d);

  float acc[12];
  #pragma unroll
  for (int d=0;d<12;++d) acc[d] = 0.f;
  #pragma unroll
  for (int a=0;a<3;++a){
    float o[12]; float ss = 0.f;
    #pragma unroll
    for (int d=0;d<12;++d){
      o[d] = diff[a][0]*vv[0][d] + diff[a][1]*vv[1][d] + diff[a][2]*vv[2][d];
      ss += o[d]*o[d];
    }
    ss += __shfl_xor(ss, 1, 64);
    ss += __shfl_xor(ss, 2, 64);
    ss += __shfl_xor(ss, 4, 64);                  // sum over 96 dims of head h
    float rms = sqrtf(ss*(1.f/96.f) + 1e-5f);
    float kk  = npad[a]*0.8f/rms;                 // includes *(1-LAMBDA_INIT)
    #pragma unroll
    for (int d=0;d<12;++d) acc[d] += o[d]*kk*sw[d];
  }
  const float idn = 1.f/denom;
  char* op = (char*)obar + (size_t)(bg*HID + h*96 + vd)*2;
  #pragma unroll
  for (int t=0;t<3;++t){
    u32x2 w;
    w[0] = f2bfbits(acc[t*4+0]*idn) | (f2bfbits(acc[t*4+1]*idn) << 16);
    w[1] = f2bfbits(acc[t*4+2]*idn) | (f2bfbits(acc[t*4+3]*idn) << 16);
    *(u32x2*)(op + t*8) = w;
  }
}

__global__ __launch_bounds__(256) void attn_kernel(
    const bf16* __restrict__ qkv, const int* __restrict__ eidx,
    const void* subw, bf16* __restrict__ obar, int b0, const float* prep)
{
  if (((const int*)prep)[0]) attn_body<bf16 >(qkv, eidx, subw, obar, b0, prep);
  else                       attn_body<float>(qkv, eidx, subw, obar, b0, prep);
}

// ---------------- launch ----------------------------------------------------
extern "C" void kernel_launch(void* const* d_in, const int* in_sizes, int n_in,
                              void* d_out, int out_size, void* d_ws, size_t ws_size,
                              hipStream_t stream)
{
  const int*  eidx = (const int*) d_in[0];
  const void* conf = d_in[1];
  const void* etab = d_in[2];
  const void* W1   = d_in[3];
  const void* b1   = d_in[4];
  const void* lng  = d_in[5];
  const void* lnb  = d_in[6];
  const void* Wq   = d_in[7];
  const void* Wk   = d_in[8];
  const void* Wv   = d_in[9];
  const void* Wo   = d_in[10];
  const void* lq1  = d_in[11];
  const void* lk1  = d_in[12];
  const void* lq2  = d_in[13];
  const void* lk2  = d_in[14];
  const void* subw = d_in[15];

  // ws layout: [prep 36KB (incl. E1 table)][obar][WqkvT][WoT][hbuf][qkv]
  const size_t PREP_B = 36864ull;
  const size_t OBAR_B = 25165824ull, WQKVT_B = 3538944ull, WOT_B = 1179648ull;
  const size_t FIXED  = PREP_B + OBAR_B + WQKVT_B + WOT_B;

  char*  ws   = (char*)d_ws;
  float* prep = (float*)ws;
  bf16*  obar = (bf16*)(ws + PREP_B);
  bf16* WqkvT = (bf16*)(ws + PREP_B + OBAR_B);
  bf16* WoT   = (bf16*)(ws + PREP_B + OBAR_B + WQKVT_B);

  // largest power-of-two chunk of batch rows that fits (min 128)
  int CB = NB;
  while (CB > 128 && FIXED + (size_t)CB*18432ull > ws_size) CB >>= 1;

  bf16* hbuf = (bf16*)(ws + FIXED);
  bf16* qkv  = (bf16*)(ws + FIXED + (size_t)CB*4608ull);

  prep_kernel<<<1, 256, 0, stream>>>(etab, W1, b1, lq1, lk1, lq2, lk2, prep);
  transpose_weights<<<dim3(24,24,4), dim3(32,8), 0, stream>>>(Wq, Wk, Wv, Wo, WqkvT, WoT, prep);

  const int nchunks = NB / CB;
  const int ctok = 3*CB;                      // tokens per chunk (mult of 384)
  for (int c = 0; c < nchunks; ++c) {
    const int b0 = c*CB, tok0 = b0*3;
    const int MT = ctok/128, NT = 18;
    embed_ln_gelu<<<ctok/64, 256, 0, stream>>>(eidx, conf, b1, lng, lnb, prep, hbuf, tok0);
    gemm_int<<<MT*NT, 256, 0, stream>>>(hbuf, WqkvT, qkv, HID, HID, HID, 2304, MT, NT);
    attn_kernel<<<CB/4, 256, 0, stream>>>(qkv, eidx, subw, obar, b0, prep);
  }

  gemm_final<<<128*6, 256, 0, stream>>>(obar, WoT, (void*)d_out, HID, HID, HID, HID, 128, 6, prep);
}

// Round 4
// 444.048 us; speedup vs baseline: 1.2780x; 1.0908x over previous
//
#include <hip/hip_runtime.h>
#include <hip/hip_bf16.h>
#include <math.h>
#include <stdint.h>

typedef __hip_bfloat16 bf16;
typedef __attribute__((ext_vector_type(8))) short short8;   // 8 x bf16 (4 VGPRs)
typedef __attribute__((ext_vector_type(4))) float f32x4;
typedef __attribute__((ext_vector_type(2))) unsigned int u32x2;

#define NB 16384
#define HID 768
#define EPS_LN 1e-5f
#define LAM_INIT 0.2f       // 0.8 - 0.6*exp(-0.3*0)

__device__ __forceinline__ float bf2f(bf16 x){ return __bfloat162float(x); }
__device__ __forceinline__ bf16  f2bf(float x){ return __float2bfloat16(x); }
__device__ __forceinline__ float bfbits(uint32_t lo16){ return __uint_as_float(lo16 << 16); }
__device__ __forceinline__ uint32_t f2bfbits(float x){
  union { float f; uint32_t u; } v; v.f = x;
  uint32_t u = v.u;
  uint32_t r = (u + 0x7fff + ((u >> 16) & 1)) >> 16;   // RNE
  return r;
}

template<typename T> __device__ __forceinline__ float ldv(const void* p, int i);
template<> __device__ __forceinline__ float ldv<float>(const void* p, int i){ return ((const float*)p)[i]; }
template<> __device__ __forceinline__ float ldv<bf16 >(const void* p, int i){ return bf2f(((const bf16*)p)[i]); }

template<typename T> __device__ __forceinline__ void stv(T* p, float v);
template<> __device__ __forceinline__ void stv<float>(float* p, float v){ *p = v; }
template<> __device__ __forceinline__ void stv<bf16 >(bf16*  p, float v){ *p = f2bf(v); }

__device__ __forceinline__ void async_copy16(void* lds, const void* g){
  __builtin_amdgcn_global_load_lds(
      (const __attribute__((address_space(1))) unsigned int*)g,
      (__attribute__((address_space(3))) unsigned int*)lds, 16, 0, 0);
}

__device__ __forceinline__ float wred64(float v){
  #pragma unroll
  for (int m = 1; m <= 32; m <<= 1) v += __shfl_xor(v, m, 64);
  return v;
}

// -------- prep_flag (1 wave): dtype detect + lambda + RoPE tables ------------
// prep floats:
//   [0]=flag(int), [1]=lam
//   [16+s*32+p]=cos, [128+s*32+p]=sin            (legacy layout, p<24)
//   [256 + (s*24+p)*2 .. +1] = packed {cos,sin}  (p<24)
//   [512+id]=mean(E1[id]), [528+id]=E[E1[id]^2], [544+id]=E[E1[id]*b1]
//   [560]=mean(b1), [561]=E[b1^2]
//   [1024 .. 1024+9*768) = E1 = etab @ W1  (9 x 768, f32)
__global__ void prep_flag(const void* etab, const void* lq1, const void* lk1,
                          const void* lq2, const void* lk2, float* prep){
  const int lane = threadIdx.x;
  const uint32_t* p = (const uint32_t*)((const char*)etab + 512);
  int v = (lane < 16) ? (int)p[lane] : 0;
  #pragma unroll
  for (int m = 1; m <= 32; m <<= 1) v |= __shfl_xor(v, m, 64);
  const int isbf = (v == 0) ? 1 : 0;
  if (lane == 0) ((int*)prep)[0] = isbf;

  float p1 = 0.f, p2 = 0.f;
  if (lane < 48){
    if (isbf){ p1 = ldv<bf16>(lq1,lane)*ldv<bf16>(lk1,lane); p2 = ldv<bf16>(lq2,lane)*ldv<bf16>(lk2,lane); }
    else     { p1 = ldv<float>(lq1,lane)*ldv<float>(lk1,lane); p2 = ldv<float>(lq2,lane)*ldv<float>(lk2,lane); }
  }
  p1 = wred64(p1); p2 = wred64(p2);
  if (lane == 0) prep[1] = expf(p1) - expf(p2) + LAM_INIT;

  if (lane < 24){
    float invf = powf(10000.f, -(float)(2*lane)/48.f);
    #pragma unroll
    for (int s=0;s<3;++s){
      float ang = (float)s*invf;
      float c = cosf(ang), sv = sinf(ang);
      prep[16  + s*32 + lane] = c;
      prep[128 + s*32 + lane] = sv;
      prep[256 + (s*24 + lane)*2    ] = c;
      prep[256 + (s*24 + lane)*2 + 1] = sv;
    }
  }
}

// -------- prep_e1 (9 blocks): E1 = etab @ W1 + closed-form LN stats ----------
// Block id computes E1[id][0..768): thread cc reads W1[e*768+cc] (coalesced).
// Stats per id via in-block reduction.  Key identity: emb@W1 = conf*(etab[id]@W1).
template<typename T>
__device__ __forceinline__ void prep_e1_body(const void* etab, const void* W1,
                                             const void* b1, float* prep,
                                             float (*red)[4]){
  const int id  = blockIdx.x;
  const int tid = threadIdx.x;
  const int wave = tid >> 6, lane = tid & 63;

  float et[32];
  #pragma unroll
  for (int e=0;e<32;++e) et[e] = ldv<T>(etab, id*32+e);

  float su=0.f, suu=0.f, sub=0.f;
  #pragma unroll
  for (int q=0;q<3;++q){
    const int cc = tid + q*256;
    float s = 0.f;
    #pragma unroll
    for (int e=0;e<32;++e) s += et[e]*ldv<T>(W1, e*HID+cc);
    prep[1024 + id*HID + cc] = s;
    float bv = ldv<T>(b1, cc);
    su += s; suu += s*s; sub += s*bv;
  }
  su = wred64(su); suu = wred64(suu); sub = wred64(sub);
  if (lane==0){ red[0][wave]=su; red[1][wave]=suu; red[2][wave]=sub; }
  __syncthreads();
  if (tid==0){
    float a=0.f,b=0.f,c=0.f;
    #pragma unroll
    for (int w=0;w<4;++w){ a+=red[0][w]; b+=red[1][w]; c+=red[2][w]; }
    prep[512+id]=a*(1.f/768.f); prep[528+id]=b*(1.f/768.f); prep[544+id]=c*(1.f/768.f);
  }
  if (id==0){
    float sb=0.f, sbb=0.f;
    #pragma unroll
    for (int q=0;q<3;++q){ float bv=ldv<T>(b1, tid+q*256); sb+=bv; sbb+=bv*bv; }
    sb=wred64(sb); sbb=wred64(sbb);
    __syncthreads();                       // red[] free again
    if (lane==0){ red[0][wave]=sb; red[1][wave]=sbb; }
    __syncthreads();
    if (tid==0){
      float a=0.f,b=0.f;
      #pragma unroll
      for (int w=0;w<4;++w){ a+=red[0][w]; b+=red[1][w]; }
      prep[560]=a*(1.f/768.f); prep[561]=b*(1.f/768.f);
    }
  }
}

__global__ __launch_bounds__(256) void prep_e1(const void* etab, const void* W1,
                                               const void* b1, float* prep){
  __shared__ float red[3][4];
  if (((const int*)prep)[0]) prep_e1_body<bf16 >(etab, W1, b1, prep, red);
  else                       prep_e1_body<float>(etab, W1, b1, prep, red);
}

// ---------------- weight transpose: (K,N) row-major -> bf16 (N,K) row-major --
template<typename T>
__device__ __forceinline__ void transpose_body(bf16 (*tile)[33], const void* src, bf16* dst){
  const int n0 = blockIdx.x*32, k0 = blockIdx.y*32;
  const int tx = threadIdx.x, ty = threadIdx.y;
  #pragma unroll
  for (int r=0;r<4;++r)
    tile[ty + 8*r][tx] = f2bf(ldv<T>(src, (k0 + ty + 8*r)*HID + n0 + tx));
  __syncthreads();
  #pragma unroll
  for (int r=0;r<4;++r)
    dst[(size_t)(n0 + ty + 8*r)*HID + k0 + tx] = tile[tx][ty + 8*r];
}

__global__ __launch_bounds__(256) void transpose_weights(
    const void* Wq, const void* Wk, const void* Wv, const void* Wo,
    bf16* __restrict__ WqkvT, bf16* __restrict__ WoT, const float* prep)
{
  __shared__ bf16 tile[32][33];
  const int z = blockIdx.z;
  const void* src = (z==0)? Wq : (z==1)? Wk : (z==2)? Wv : Wo;
  bf16* dst = (z<3)? (WqkvT + (size_t)z*HID*HID) : WoT;
  if (((const int*)prep)[0]) transpose_body<bf16 >(tile, src, dst);
  else                       transpose_body<float>(tile, src, dst);
}

// -------- embed via E1 table: h = gelu(LN(conf*E1[id] + b1)) -----------------
// Closed-form LN stats (no reductions).  4 tokens per wave (grid ctok/16,
// ~6 blocks/CU) to hide the erf-chain latency with TLP.
template<typename T>
__device__ __forceinline__ void embed_body(
    const int* eidx, const void* conf, const void* b1, const void* lng,
    const void* lnb, const float* prep, bf16* hout, int tok0)
{
  const int wave = threadIdx.x >> 6, lane = threadIdx.x & 63;
  const int t0 = blockIdx.x*16 + wave*4;
  const int c  = lane*12;
  float bb[12], gg[12], be[12];
  #pragma unroll
  for (int d=0;d<12;++d){ bb[d]=ldv<T>(b1,c+d); gg[d]=ldv<T>(lng,c+d); be[d]=ldv<T>(lnb,c+d); }
  const float m_b = prep[560], s_bb = prep[561];
  const float* E1 = prep + 1024;

  #pragma unroll
  for (int tt = 0; tt < 4; ++tt){
    const int tl = t0 + tt, tg = tok0 + tl;
    int id = eidx[tg]; if (id < 0) id = 8;
    const float cf = ldv<T>(conf, tg);
    const float4* ep = (const float4*)(E1 + id*HID + c);
    float4 u0 = ep[0], u1 = ep[1], u2 = ep[2];
    float u[12] = {u0.x,u0.y,u0.z,u0.w, u1.x,u1.y,u1.z,u1.w, u2.x,u2.y,u2.z,u2.w};
    const float mu  = cf*prep[512+id] + m_b;
    const float ex2 = cf*cf*prep[528+id] + 2.f*cf*prep[544+id] + s_bb;
    const float var = ex2 - mu*mu;
    const float rs  = rsqrtf(fmaxf(var, 0.f) + EPS_LN);
    uint32_t w[6];
    #pragma unroll
    for (int d=0;d<6;++d){
      float x0 = cf*u[2*d]   + bb[2*d];
      float x1 = cf*u[2*d+1] + bb[2*d+1];
      float y0 = (x0-mu)*rs*gg[2*d]   + be[2*d];
      float y1 = (x1-mu)*rs*gg[2*d+1] + be[2*d+1];
      float g0 = 0.5f*y0*(1.f + erff(y0*0.70710678118f));
      float g1 = 0.5f*y1*(1.f + erff(y1*0.70710678118f));
      w[d] = f2bfbits(g0) | (f2bfbits(g1) << 16);
    }
    char* op = (char*)hout + (size_t)(tl*HID + c)*2;
    ((u32x2*)op)[0] = (u32x2){w[0],w[1]};
    ((u32x2*)op)[1] = (u32x2){w[2],w[3]};
    ((u32x2*)op)[2] = (u32x2){w[4],w[5]};
  }
}

__global__ __launch_bounds__(256) void embed_ln_gelu(
    const int* __restrict__ eidx, const void* conf, const void* b1,
    const void* lng, const void* lnb, const float* prep,
    bf16* __restrict__ hout, int tok0)
{
  if (((const int*)prep)[0]) embed_body<bf16 >(eidx, conf, b1, lng, lnb, prep, hout, tok0);
  else                       embed_body<float>(eidx, conf, b1, lng, lnb, prep, hout, tok0);
}

// ------- 128x128 MFMA GEMM: dbuf pipeline + XCD swizzle + LDS XOR swizzle ----
template<typename OutT>
__device__ __forceinline__ void gemm_body(
    bf16* sA, bf16* sB,     // each 2*128*64 elements (two buffers)
    const bf16* __restrict__ A, const bf16* __restrict__ Bt, OutT* __restrict__ C,
    int K, int lda, int ldb, int ldc, int MT, int NT)
{
  int bid = blockIdx.x;
  int mt, nt;
  if ((MT & 7) == 0) {
    int x = bid & 7, j = bid >> 3;
    nt = j % NT;
    mt = x * (MT >> 3) + j / NT;
  } else { nt = bid % NT; mt = bid / NT; }

  const int tid = threadIdx.x;
  const int wave = tid >> 6, lane = tid & 63;
  const int m0 = mt * 128, n0 = nt * 128;
  const int wm = wave >> 1, wn = wave & 1;

  f32x4 acc[4][4];
  #pragma unroll
  for (int i=0;i<4;++i)
    #pragma unroll
    for (int j=0;j<4;++j) acc[i][j] = (f32x4){0.f,0.f,0.f,0.f};

  const char* Ag = (const char*)(A  + (size_t)m0 * lda);
  const char* Bg = (const char*)(Bt + (size_t)n0 * ldb);
  const int r8  = lane >> 3;                       // row within 8-row group (0..7)
  const int cBx = ((lane & 7) ^ r8) * 16;          // XOR-permuted k-group source

  #define STAGE(buf, kt) do {                                                   \
    _Pragma("unroll")                                                           \
    for (int ii = 0; ii < 4; ++ii) {                                            \
      const int i_ = wave*4 + ii;                                               \
      const int row_ = i_*8 + r8;                                               \
      async_copy16((char*)sA + (buf)*16384 + i_*1024 + lane*16,                 \
                   Ag + ((size_t)row_*lda + (kt))*2 + cBx);                     \
      async_copy16((char*)sB + (buf)*16384 + i_*1024 + lane*16,                 \
                   Bg + ((size_t)row_*ldb + (kt))*2 + cBx);                     \
    }                                                                           \
  } while(0)

  STAGE(0, 0);
  int cur = 0;
  const int rxor = (lane & 7) << 3;                // reader phys-k XOR (row&7)*8
  for (int kt = 0; kt < K; kt += 64) {
    __syncthreads();
    if (kt + 64 < K) STAGE(cur^1, kt + 64);   // prefetch overlaps compute below
    const bf16* pA = sA + cur*8192;
    const bf16* pB = sB + cur*8192;
    #pragma unroll
    for (int ks = 0; ks < 64; ks += 32) {
      const int kq = (ks + (lane >> 4)*8) ^ rxor;
      short8 af[4], bfv[4];
      #pragma unroll
      for (int i=0;i<4;++i)
        af[i]  = *(const short8*)&pA[(wm*64 + i*16 + (lane&15))*64 + kq];
      #pragma unroll
      for (int j=0;j<4;++j)
        bfv[j] = *(const short8*)&pB[(wn*64 + j*16 + (lane&15))*64 + kq];
      #pragma unroll
      for (int i=0;i<4;++i)
        #pragma unroll
        for (int j=0;j<4;++j)
          acc[i][j] = __builtin_amdgcn_mfma_f32_16x16x32_bf16(af[i], bfv[j], acc[i][j], 0,0,0);
    }
    cur ^= 1;
  }
  #undef STAGE

  const int rb = (lane>>4)*4, cb = lane & 15;   // C/D: col=lane&15, row=quad*4+reg
  #pragma unroll
  for (int i=0;i<4;++i)
    #pragma unroll
    for (int r=0;r<4;++r) {
      const int grow = m0 + wm*64 + i*16 + rb + r;
      OutT* Cp = C + (size_t)grow*ldc + n0 + wn*64 + cb;
      #pragma unroll
      for (int j=0;j<4;++j) stv<OutT>(Cp + j*16, acc[i][j][r]);
    }
}

__global__ __launch_bounds__(256) void gemm_int(
    const bf16* __restrict__ A, const bf16* __restrict__ Bt, bf16* __restrict__ C,
    int K, int lda, int ldb, int ldc, int MT, int NT)
{
  __shared__ __align__(16) bf16 sA[2*128*64];   // 32 KB
  __shared__ __align__(16) bf16 sB[2*128*64];   // 32 KB
  gemm_body<bf16>(sA, sB, A, Bt, C, K, lda, ldb, ldc, MT, NT);
}

__global__ __launch_bounds__(256) void gemm_final(
    const bf16* __restrict__ A, const bf16* __restrict__ Bt, void* C,
    int K, int lda, int ldb, int ldc, int MT, int NT, const float* prep)
{
  __shared__ __align__(16) bf16 sA[2*128*64];
  __shared__ __align__(16) bf16 sB[2*128*64];
  if (((const int*)prep)[0]) gemm_body<bf16 >(sA, sB, A, Bt, (bf16*)C,  K, lda, ldb, ldc, MT, NT);
  else                       gemm_body<float>(sA, sB, A, Bt, (float*)C, K, lda, ldb, ldc, MT, NT);
}

// ---------------- attention: one wave per batch row (all 8 heads) ------------
// lane = h*8 + u, u = g*4 + qd.  36 shfl/wave for 8 heads; every qkv byte read
// exactly once, 8B loads.
template<typename T>
__device__ __forceinline__ void attn_body(
    const bf16* __restrict__ qkv, const int* __restrict__ eidx,
    const void* subw, bf16* __restrict__ obar, int b0, const float* prep)
{
  const int bl = blockIdx.x*4 + (threadIdx.x>>6);   // chunk-local batch row
  const int bg = b0 + bl;                           // global batch row
  const int lane = threadIdx.x & 63;
  const int h  = lane >> 3;
  const int u  = lane & 7;
  const int g  = u >> 2;
  const int qd = u & 3;

  float npad[3];
  #pragma unroll
  for (int s=0;s<3;++s){ int id = eidx[bg*3+s]; npad[s] = (id < 0 || id == 8) ? 0.f : 1.f; }
  float denom = npad[0]+npad[1]+npad[2]; if (denom < 1.f) denom = 1.f;
  const float lam = prep[1];
  const float2* pk = (const float2*)(prep + 256);

  const char* base = (const char*)(qkv + (size_t)bl*3*2304);
  const int qoff = (2*h+g)*48 + qd*12;              // element offset in token row

  u32x2 qw[3][3], kw[3][3];
  #pragma unroll
  for (int s=0;s<3;++s){
    const char* qp = base + (size_t)(s*2304 + qoff)*2;
    const char* kp = qp + 768*2;
    #pragma unroll
    for (int t=0;t<3;++t){
      qw[s][t] = *(const u32x2*)(qp + t*8);
      kw[s][t] = *(const u32x2*)(kp + t*8);
    }
  }

  float sc[3][3];
  #pragma unroll
  for (int a=0;a<3;++a){ sc[a][0]=0.f; sc[a][1]=0.f; sc[a][2]=0.f; }
  #pragma unroll
  for (int j=0;j<6;++j){
    float qr1[3], qr2[3], kr1[3], kr2[3];
    #pragma unroll
    for (int s=0;s<3;++s){
      float2 cs = pk[s*24 + qd*6 + j];
      uint32_t qu = qw[s][j>>1][j&1], ku = kw[s][j>>1][j&1];
      float q1 = bfbits(qu & 0xffffu), q2 = bfbits(qu >> 16);
      float k1 = bfbits(ku & 0xffffu), k2 = bfbits(ku >> 16);
      qr1[s] = q1*cs.x - q2*cs.y;  qr2[s] = q1*cs.y + q2*cs.x;
      kr1[s] = k1*cs.x - k2*cs.y;  kr2[s] = k1*cs.y + k2*cs.x;
    }
    #pragma unroll
    for (int a=0;a<3;++a)
      #pragma unroll
      for (int b=0;b<3;++b) sc[a][b] += qr1[a]*kr1[b] + qr2[a]*kr2[b];
  }
  #pragma unroll
  for (int a=0;a<3;++a)
    #pragma unroll
    for (int b=0;b<3;++b){
      float v = sc[a][b];
      v += __shfl_xor(v, 1, 64);
      v += __shfl_xor(v, 2, 64);
      sc[a][b] = v;
    }

  const float scale = 0.14433756729740643f;  // 48^-0.5
  float att[3][3];
  #pragma unroll
  for (int a=0;a<3;++a){
    float s0 = sc[a][0]*scale + (npad[0] > 0.f ? 0.f : -1e30f);
    float s1 = sc[a][1]*scale + (npad[1] > 0.f ? 0.f : -1e30f);
    float s2 = sc[a][2]*scale + (npad[2] > 0.f ? 0.f : -1e30f);
    float mx = fmaxf(s0, fmaxf(s1, s2));
    float e0 = expf(s0-mx), e1 = expf(s1-mx), e2 = expf(s2-mx);
    float inv = 1.f/(e0+e1+e2);
    att[a][0]=e0*inv; att[a][1]=e1*inv; att[a][2]=e2*inv;
  }
  float diff[3][3];
  #pragma unroll
  for (int a=0;a<3;++a)
    #pragma unroll
    for (int b=0;b<3;++b){
      float other = __shfl_xor(att[a][b], 4, 64);
      diff[a][b] = (g==0) ? (att[a][b] - lam*other) : (other - lam*att[a][b]);
    }

  const int vd = u*12;
  float vv[3][12];
  #pragma unroll
  for (int s=0;s<3;++s){
    const char* vp = base + (size_t)(s*2304 + 1536 + h*96 + vd)*2;
    #pragma unroll
    for (int t=0;t<3;++t){
      u32x2 w = *(const u32x2*)(vp + t*8);
      vv[s][t*4+0] = bfbits(w[0] & 0xffffu);
      vv[s][t*4+1] = bfbits(w[0] >> 16);
      vv[s][t*4+2] = bfbits(w[1] & 0xffffu);
      vv[s][t*4+3] = bfbits(w[1] >> 16);
    }
  }
  float sw[12];
  #pragma unroll
  for (int d=0;d<12;++d) sw[d] = ldv<T>(subw, vd + d);

  float acc[12];
  #pragma unroll
  for (int d=0;d<12;++d) acc[d] = 0.f;
  #pragma unroll
  for (int a=0;a<3;++a){
    float o[12]; float ss = 0.f;
    #pragma unroll
    for (int d=0;d<12;++d){
      o[d] = diff[a][0]*vv[0][d] + diff[a][1]*vv[1][d] + diff[a][2]*vv[2][d];
      ss += o[d]*o[d];
    }
    ss += __shfl_xor(ss, 1, 64);
    ss += __shfl_xor(ss, 2, 64);
    ss += __shfl_xor(ss, 4, 64);                  // sum over 96 dims of head h
    float rms = sqrtf(ss*(1.f/96.f) + 1e-5f);
    float kk  = npad[a]*0.8f/rms;                 // includes *(1-LAMBDA_INIT)
    #pragma unroll
    for (int d=0;d<12;++d) acc[d] += o[d]*kk*sw[d];
  }
  const float idn = 1.f/denom;
  char* op = (char*)obar + (size_t)(bg*HID + h*96 + vd)*2;
  #pragma unroll
  for (int t=0;t<3;++t){
    u32x2 w;
    w[0] = f2bfbits(acc[t*4+0]*idn) | (f2bfbits(acc[t*4+1]*idn) << 16);
    w[1] = f2bfbits(acc[t*4+2]*idn) | (f2bfbits(acc[t*4+3]*idn) << 16);
    *(u32x2*)(op + t*8) = w;
  }
}

__global__ __launch_bounds__(256) void attn_kernel(
    const bf16* __restrict__ qkv, const int* __restrict__ eidx,
    const void* subw, bf16* __restrict__ obar, int b0, const float* prep)
{
  if (((const int*)prep)[0]) attn_body<bf16 >(qkv, eidx, subw, obar, b0, prep);
  else                       attn_body<float>(qkv, eidx, subw, obar, b0, prep);
}

// ---------------- launch ----------------------------------------------------
extern "C" void kernel_launch(void* const* d_in, const int* in_sizes, int n_in,
                              void* d_out, int out_size, void* d_ws, size_t ws_size,
                              hipStream_t stream)
{
  const int*  eidx = (const int*) d_in[0];
  const void* conf = d_in[1];
  const void* etab = d_in[2];
  const void* W1   = d_in[3];
  const void* b1   = d_in[4];
  const void* lng  = d_in[5];
  const void* lnb  = d_in[6];
  const void* Wq   = d_in[7];
  const void* Wk   = d_in[8];
  const void* Wv   = d_in[9];
  const void* Wo   = d_in[10];
  const void* lq1  = d_in[11];
  const void* lk1  = d_in[12];
  const void* lq2  = d_in[13];
  const void* lk2  = d_in[14];
  const void* subw = d_in[15];

  // ws layout: [prep 36KB (incl. E1 table)][obar][WqkvT][WoT][hbuf][qkv]
  const size_t PREP_B = 36864ull;
  const size_t OBAR_B = 25165824ull, WQKVT_B = 3538944ull, WOT_B = 1179648ull;
  const size_t FIXED  = PREP_B + OBAR_B + WQKVT_B + WOT_B;

  char*  ws   = (char*)d_ws;
  float* prep = (float*)ws;
  bf16*  obar = (bf16*)(ws + PREP_B);
  bf16* WqkvT = (bf16*)(ws + PREP_B + OBAR_B);
  bf16* WoT   = (bf16*)(ws + PREP_B + OBAR_B + WQKVT_B);

  // largest power-of-two chunk of batch rows that fits (min 128)
  int CB = NB;
  while (CB > 128 && FIXED + (size_t)CB*18432ull > ws_size) CB >>= 1;

  bf16* hbuf = (bf16*)(ws + FIXED);
  bf16* qkv  = (bf16*)(ws + FIXED + (size_t)CB*4608ull);

  prep_flag<<<1, 64, 0, stream>>>(etab, lq1, lk1, lq2, lk2, prep);
  prep_e1<<<9, 256, 0, stream>>>(etab, W1, b1, prep);
  transpose_weights<<<dim3(24,24,4), dim3(32,8), 0, stream>>>(Wq, Wk, Wv, Wo, WqkvT, WoT, prep);

  const int nchunks = NB / CB;
  const int ctok = 3*CB;                      // tokens per chunk (mult of 384)
  for (int c = 0; c < nchunks; ++c) {
    const int b0 = c*CB, tok0 = b0*3;
    const int MT = ctok/128, NT = 18;
    embed_ln_gelu<<<ctok/16, 256, 0, stream>>>(eidx, conf, b1, lng, lnb, prep, hbuf, tok0);
    gemm_int<<<MT*NT, 256, 0, stream>>>(hbuf, WqkvT, qkv, HID, HID, HID, 2304, MT, NT);
    attn_kernel<<<CB/4, 256, 0, stream>>>(qkv, eidx, subw, obar, b0, prep);
  }

  gemm_final<<<128*6, 256, 0, stream>>>(obar, WoT, (void*)d_out, HID, HID, HID, HID, 128, 6, prep);
}